// Round 1
// baseline (1565.200 us; speedup 1.0000x reference)
//
#include <hip/hip_runtime.h>
#include <math.h>

#define N_NODES 50000
#define N_EDGES 1600000
#define IN_DIM  128
#define OUT_DIM 32
#define N_HEADS 4
#define WH_DIM  (N_HEADS * OUT_DIM)   // 128

// ---------------------------------------------------------------------------
// edge_index may arrive as int32 (harness default) or int64 (reference dtype).
// Detect at runtime: for int64, every odd 32-bit word is a zero hi-word.
// ---------------------------------------------------------------------------
__device__ __forceinline__ void load_edge(const void* eidx, int is32, int e,
                                          int& s, int& d) {
    if (is32) {
        const int2 v = ((const int2*)eidx)[e];
        s = v.x; d = v.y;
    } else {
        const longlong2 v = ((const longlong2*)eidx)[e];
        s = (int)v.x; d = (int)v.y;
    }
}

__global__ void k_detect(const int* __restrict__ eidx, int* __restrict__ flag) {
    int i = blockIdx.x * blockDim.x + threadIdx.x;
    int stride = gridDim.x * blockDim.x;
    int r = 0;
    // odd 32-bit words within the first 2*N_EDGES words (safe for both dtypes)
    for (int w = 2 * i + 1; w < 2 * N_EDGES; w += 2 * stride) r |= eidx[w];
    unsigned long long b = __ballot(r != 0);
    if ((threadIdx.x & 63) == 0 && b) atomicOr(flag, 1);
}

__global__ void k_init_max(float* __restrict__ maxbuf) {
    int i = blockIdx.x * blockDim.x + threadIdx.x;
    if (i < N_NODES * N_HEADS) maxbuf[i] = -INFINITY;
}

// float atomic max via sign-split int/uint atomics (works with -inf init)
__device__ __forceinline__ void atomicMaxF(float* addr, float v) {
    if (v >= 0.0f) atomicMax((int*)addr, __float_as_int(v));
    else           atomicMin((unsigned int*)addr, __float_as_uint(v));
}

// ---------------------------------------------------------------------------
// Wh = einsum('ni,hio->nho'); also s_src[n,h] = <Wh[n,h,:], a_src[h,:]>,
//                                  s_dst[n,h] = <Wh[n,h,:], a_dst[h,:]>
// 1 wave per node (64 threads, float2 per thread), weight staged in LDS.
// ---------------------------------------------------------------------------
__global__ __launch_bounds__(256) void k_wh(
        const float* __restrict__ x, const float* __restrict__ weight,
        const float* __restrict__ attn, float* __restrict__ Wh,
        float* __restrict__ s_src, float* __restrict__ s_dst) {
    __shared__ float wl[N_HEADS * IN_DIM * OUT_DIM];   // 16384 f32 = 64 KB
    for (int k = threadIdx.x; k < N_HEADS * IN_DIM * OUT_DIM; k += 256)
        wl[k] = weight[k];
    __syncthreads();

    const int node = blockIdx.x * 4 + (threadIdx.x >> 6);
    const int t  = threadIdx.x & 63;
    const int h  = t >> 4;          // 4 heads x 16 lanes
    const int o2 = (t & 15) * 2;    // 2 output dims per lane

    const float* xr = x + (size_t)node * IN_DIM;
    const float* wp = wl + h * (IN_DIM * OUT_DIM) + o2;
    float2 acc = {0.0f, 0.0f};
#pragma unroll 8
    for (int i = 0; i < IN_DIM; ++i) {
        float  xv = xr[i];
        float2 wv = *(const float2*)(wp + i * OUT_DIM);
        acc.x += xv * wv.x;
        acc.y += xv * wv.y;
    }
    *(float2*)(Wh + (size_t)node * WH_DIM + h * OUT_DIM + o2) = acc;

    // per-head attention dots, reduced over the 16-lane o-group
    float as0 = attn[h * 64 + o2],      as1 = attn[h * 64 + o2 + 1];
    float ad0 = attn[h * 64 + 32 + o2], ad1 = attn[h * 64 + 32 + o2 + 1];
    float vs = acc.x * as0 + acc.y * as1;
    float vd = acc.x * ad0 + acc.y * ad1;
#pragma unroll
    for (int off = 8; off; off >>= 1) {
        vs += __shfl_xor(vs, off);
        vd += __shfl_xor(vd, off);
    }
    if ((t & 15) == 0) {
        s_src[node * N_HEADS + h] = vs;
        s_dst[node * N_HEADS + h] = vd;
    }
}

// ---------------------------------------------------------------------------
// e = leaky_relu(s_src[src] + s_dst[dst]); atomic segment-max over dst
// ---------------------------------------------------------------------------
__global__ __launch_bounds__(256) void k_edge1(
        const void* __restrict__ eidx, const int* __restrict__ flag,
        const float* __restrict__ s_src, const float* __restrict__ s_dst,
        float* __restrict__ ebuf, float* __restrict__ maxbuf) {
    int e = blockIdx.x * 256 + threadIdx.x;
    if (e >= N_EDGES) return;
    int is32 = *flag;
    int s, d;
    load_edge(eidx, is32, e, s, d);
    float4 ss = *(const float4*)(s_src + s * 4);
    float4 sd = *(const float4*)(s_dst + d * 4);
    float4 ev;
    ev.x = ss.x + sd.x; ev.y = ss.y + sd.y;
    ev.z = ss.z + sd.z; ev.w = ss.w + sd.w;
    ev.x = ev.x > 0.0f ? ev.x : 0.2f * ev.x;
    ev.y = ev.y > 0.0f ? ev.y : 0.2f * ev.y;
    ev.z = ev.z > 0.0f ? ev.z : 0.2f * ev.z;
    ev.w = ev.w > 0.0f ? ev.w : 0.2f * ev.w;
    *(float4*)(ebuf + (size_t)e * 4) = ev;
    atomicMaxF(maxbuf + d * 4 + 0, ev.x);
    atomicMaxF(maxbuf + d * 4 + 1, ev.y);
    atomicMaxF(maxbuf + d * 4 + 2, ev.z);
    atomicMaxF(maxbuf + d * 4 + 3, ev.w);
}

// ---------------------------------------------------------------------------
// exp(e - max[dst]) in place; atomic segment-sum over dst
// ---------------------------------------------------------------------------
__global__ __launch_bounds__(256) void k_edge2(
        const void* __restrict__ eidx, const int* __restrict__ flag,
        float* __restrict__ ebuf, const float* __restrict__ maxbuf,
        float* __restrict__ sumbuf) {
    int e = blockIdx.x * 256 + threadIdx.x;
    if (e >= N_EDGES) return;
    int is32 = *flag;
    int s, d;
    load_edge(eidx, is32, e, s, d);
    float4 ev = *(const float4*)(ebuf + (size_t)e * 4);
    float4 mv = *(const float4*)(maxbuf + d * 4);
    float4 ex;
    ex.x = __expf(ev.x - mv.x);
    ex.y = __expf(ev.y - mv.y);
    ex.z = __expf(ev.z - mv.z);
    ex.w = __expf(ev.w - mv.w);
    *(float4*)(ebuf + (size_t)e * 4) = ex;
    atomicAdd(sumbuf + d * 4 + 0, ex.x);
    atomicAdd(sumbuf + d * 4 + 1, ex.y);
    atomicAdd(sumbuf + d * 4 + 2, ex.z);
    atomicAdd(sumbuf + d * 4 + 3, ex.w);
}

// ---------------------------------------------------------------------------
// alpha = exp/(sum[dst]+1e-9)  (written to d_out alpha region, in place over exp)
// out[dst, :] += alpha[h] * Wh[src, :]   (128 threads per edge, atomic f32)
// ---------------------------------------------------------------------------
__global__ __launch_bounds__(256) void k_edge3(
        const void* __restrict__ eidx, const int* __restrict__ flag,
        const float* __restrict__ Wh, const float* __restrict__ sumbuf,
        float* __restrict__ ebuf, float* __restrict__ out_h) {
    const int eg = threadIdx.x >> 7;       // 2 edges per block
    const int t  = threadIdx.x & 127;
    const int e  = blockIdx.x * 2 + eg;
    const int h  = t >> 5;
    int is32 = *flag;
    int s, d;
    load_edge(eidx, is32, e, s, d);

    float ex = ebuf[(size_t)e * 4 + h];
    float sm = sumbuf[d * 4 + h];
    float a  = ex / (sm + 1e-9f);
    float w  = Wh[(size_t)s * WH_DIM + t];

    float alpha_t = 0.0f;
    if (t < 4) alpha_t = ebuf[(size_t)e * 4 + t] / (sumbuf[d * 4 + t] + 1e-9f);
    __syncthreads();                        // all exp reads done before overwrite
    if (t < 4) ebuf[(size_t)e * 4 + t] = alpha_t;

    atomicAdd(out_h + (size_t)d * WH_DIM + t, a * w);
}

// ---------------------------------------------------------------------------
extern "C" void kernel_launch(void* const* d_in, const int* in_sizes, int n_in,
                              void* d_out, int out_size, void* d_ws, size_t ws_size,
                              hipStream_t stream) {
    const float* x      = (const float*)d_in[0];
    const void*  eidx   = d_in[1];
    const float* weight = (const float*)d_in[2];
    const float* attn   = (const float*)d_in[3];

    float* out   = (float*)d_out;
    float* out_h = out;                                   // [N_NODES, 128]
    float* ebuf  = out + (size_t)N_NODES * WH_DIM;        // [N_EDGES, 4] alpha/scratch

    // workspace layout (16B-aligned chunks)
    char*  ws     = (char*)d_ws;
    float* sumbuf = (float*)ws;                           // 200000 f32 = 800000 B
    int*   flag   = (int*)(ws + 800000);                  // 4 B (+12 pad)
    float* maxbuf = (float*)(ws + 800016);                // 200000 f32
    float* Wh     = (float*)(ws + 1600016);               // 6.4M f32 = 25.6 MB
    float* s_src  = (float*)(ws + 1600016 + 25600000);    // 200000 f32
    float* s_dst  = (float*)(ws + 1600016 + 25600000 + 800000);

    hipMemsetAsync(out_h, 0, (size_t)N_NODES * WH_DIM * sizeof(float), stream);
    hipMemsetAsync(ws, 0, 800000 + 4, stream);            // sumbuf + flag

    k_init_max<<<(N_NODES * N_HEADS + 255) / 256, 256, 0, stream>>>(maxbuf);
    k_detect<<<512, 256, 0, stream>>>((const int*)eidx, flag);
    k_wh<<<N_NODES / 4, 256, 0, stream>>>(x, weight, attn, Wh, s_src, s_dst);
    k_edge1<<<(N_EDGES + 255) / 256, 256, 0, stream>>>(eidx, flag, s_src, s_dst,
                                                       ebuf, maxbuf);
    k_edge2<<<(N_EDGES + 255) / 256, 256, 0, stream>>>(eidx, flag, ebuf, maxbuf,
                                                       sumbuf);
    k_edge3<<<N_EDGES / 2, 256, 0, stream>>>(eidx, flag, Wh, sumbuf, ebuf, out_h);
}

// Round 2
// 707.840 us; speedup vs baseline: 2.2112x; 2.2112x over previous
//
#include <hip/hip_runtime.h>
#include <math.h>

#define N_NODES 50000
#define N_EDGES 1600000
#define IN_DIM  128
#define OUT_DIM 32
#define N_HEADS 4
#define WH_DIM  (N_HEADS * OUT_DIM)   // 128
#define CAP     128                   // per-node LDS edge cache (max deg ~58)

// ---------------------------------------------------------------------------
// edge_index may arrive as int32 (harness default) or int64 (reference dtype).
// Detect at runtime: for int64, every odd 32-bit word is a zero hi-word.
// ---------------------------------------------------------------------------
__device__ __forceinline__ void load_edge(const void* eidx, int is32, int e,
                                          int& s, int& d) {
    if (is32) {
        const int2 v = ((const int2*)eidx)[e];
        s = v.x; d = v.y;
    } else {
        const longlong2 v = ((const longlong2*)eidx)[e];
        s = (int)v.x; d = (int)v.y;
    }
}

__global__ void k_detect(const int* __restrict__ eidx, int* __restrict__ flag) {
    int i = blockIdx.x * blockDim.x + threadIdx.x;
    int stride = gridDim.x * blockDim.x;
    int r = 0;
    for (int w = 2 * i + 1; w < 2 * N_EDGES; w += 2 * stride) r |= eidx[w];
    unsigned long long b = __ballot(r != 0);
    if ((threadIdx.x & 63) == 0 && b) atomicOr(flag, 1);
}

// ---------------------------------------------------------------------------
// Wh = einsum('ni,hio->nho'); also s_src[n,h] = <Wh[n,h,:], a_src[h,:]>,
//                                  s_dst[n,h] = <Wh[n,h,:], a_dst[h,:]>
// ---------------------------------------------------------------------------
__global__ __launch_bounds__(256) void k_wh(
        const float* __restrict__ x, const float* __restrict__ weight,
        const float* __restrict__ attn, float* __restrict__ Wh,
        float* __restrict__ s_src, float* __restrict__ s_dst) {
    __shared__ float wl[N_HEADS * IN_DIM * OUT_DIM];   // 64 KB
    for (int k = threadIdx.x; k < N_HEADS * IN_DIM * OUT_DIM; k += 256)
        wl[k] = weight[k];
    __syncthreads();

    const int node = blockIdx.x * 4 + (threadIdx.x >> 6);
    const int t  = threadIdx.x & 63;
    const int h  = t >> 4;
    const int o2 = (t & 15) * 2;

    const float* xr = x + (size_t)node * IN_DIM;
    const float* wp = wl + h * (IN_DIM * OUT_DIM) + o2;
    float2 acc = {0.0f, 0.0f};
#pragma unroll 8
    for (int i = 0; i < IN_DIM; ++i) {
        float  xv = xr[i];
        float2 wv = *(const float2*)(wp + i * OUT_DIM);
        acc.x += xv * wv.x;
        acc.y += xv * wv.y;
    }
    *(float2*)(Wh + (size_t)node * WH_DIM + h * OUT_DIM + o2) = acc;

    float as0 = attn[h * 64 + o2],      as1 = attn[h * 64 + o2 + 1];
    float ad0 = attn[h * 64 + 32 + o2], ad1 = attn[h * 64 + 32 + o2 + 1];
    float vs = acc.x * as0 + acc.y * as1;
    float vd = acc.x * ad0 + acc.y * ad1;
#pragma unroll
    for (int off = 8; off; off >>= 1) {
        vs += __shfl_xor(vs, off);
        vd += __shfl_xor(vd, off);
    }
    if ((t & 15) == 0) {
        s_src[node * N_HEADS + h] = vs;
        s_dst[node * N_HEADS + h] = vd;
    }
}

// ---------------------------------------------------------------------------
// CSR build: count -> scan -> scatter
// ---------------------------------------------------------------------------
__global__ __launch_bounds__(256) void k_count(
        const void* __restrict__ eidx, const int* __restrict__ flag,
        int* __restrict__ cnt) {
    int e = blockIdx.x * 256 + threadIdx.x;
    if (e >= N_EDGES) return;
    int s, d;
    load_edge(eidx, *flag, e, s, d);
    atomicAdd(cnt + d, 1);
}

__global__ __launch_bounds__(1024) void k_scan(
        const int* __restrict__ cnt, int* __restrict__ off,
        int* __restrict__ woff) {
    __shared__ int part[1024];
    const int t  = threadIdx.x;
    const int CH = (N_NODES + 1023) / 1024;            // 49
    const int base = t * CH;
    int s = 0;
    for (int i = 0; i < CH; ++i) {
        int idx = base + i;
        if (idx < N_NODES) s += cnt[idx];
    }
    part[t] = s;
    __syncthreads();
    for (int d = 1; d < 1024; d <<= 1) {               // Hillis-Steele inclusive
        int u = (t >= d) ? part[t - d] : 0;
        __syncthreads();
        part[t] += u;
        __syncthreads();
    }
    int run = part[t] - s;                              // exclusive prefix
    for (int i = 0; i < CH; ++i) {
        int idx = base + i;
        if (idx < N_NODES) {
            off[idx]  = run;
            woff[idx] = run;
            run += cnt[idx];
        }
    }
    if (t == 1023) off[N_NODES] = part[1023];
}

__global__ __launch_bounds__(256) void k_scatter(
        const void* __restrict__ eidx, const int* __restrict__ flag,
        int* __restrict__ woff, int* __restrict__ csr_src,
        int* __restrict__ csr_eid) {
    int e = blockIdx.x * 256 + threadIdx.x;
    if (e >= N_EDGES) return;
    int s, d;
    load_edge(eidx, *flag, e, s, d);
    int pos = atomicAdd(woff + d, 1);
    csr_src[pos] = s;
    csr_eid[pos] = e;
}

// ---------------------------------------------------------------------------
// One wave per dst node: segment softmax + weighted accumulate, no atomics.
// ---------------------------------------------------------------------------
__device__ __forceinline__ float lrelu(float v) {
    return v > 0.0f ? v : 0.2f * v;
}

__global__ __launch_bounds__(256) void k_node(
        const int* __restrict__ off, const int* __restrict__ csr_src,
        const int* __restrict__ csr_eid,
        const float* __restrict__ s_src, const float* __restrict__ s_dst,
        const float* __restrict__ Wh,
        float* __restrict__ ebuf, float* __restrict__ out_h) {
    __shared__ int    sbuf[4][CAP];
    __shared__ float4 e4b[4][CAP];                      // e -> ex -> alpha
    const int wv = threadIdx.x >> 6;
    const int t  = threadIdx.x & 63;
    const int n  = blockIdx.x * 4 + wv;
    const int beg = off[n], end = off[n + 1], deg = end - beg;

    const float4 sd = *(const float4*)(s_dst + n * 4);

    // Phase A: e = leaky_relu(s_src[src] + s_dst[n]); cache; running max
    float4 mx = {-INFINITY, -INFINITY, -INFINITY, -INFINITY};
    for (int l = t; l < deg; l += 64) {
        int s = csr_src[beg + l];
        float4 ss = *(const float4*)(s_src + s * 4);
        float4 e;
        e.x = lrelu(ss.x + sd.x); e.y = lrelu(ss.y + sd.y);
        e.z = lrelu(ss.z + sd.z); e.w = lrelu(ss.w + sd.w);
        if (l < CAP) { sbuf[wv][l] = s; e4b[wv][l] = e; }
        mx.x = fmaxf(mx.x, e.x); mx.y = fmaxf(mx.y, e.y);
        mx.z = fmaxf(mx.z, e.z); mx.w = fmaxf(mx.w, e.w);
    }
#pragma unroll
    for (int o = 32; o; o >>= 1) {
        mx.x = fmaxf(mx.x, __shfl_xor(mx.x, o));
        mx.y = fmaxf(mx.y, __shfl_xor(mx.y, o));
        mx.z = fmaxf(mx.z, __shfl_xor(mx.z, o));
        mx.w = fmaxf(mx.w, __shfl_xor(mx.w, o));
    }

    // Phase B: ex = exp(e - mx); cache; running sum
    float4 sum = {0.0f, 0.0f, 0.0f, 0.0f};
    for (int l = t; l < deg; l += 64) {
        float4 e;
        if (l < CAP) e = e4b[wv][l];
        else {
            int s = csr_src[beg + l];
            float4 ss = *(const float4*)(s_src + s * 4);
            e.x = lrelu(ss.x + sd.x); e.y = lrelu(ss.y + sd.y);
            e.z = lrelu(ss.z + sd.z); e.w = lrelu(ss.w + sd.w);
        }
        float4 ex;
        ex.x = __expf(e.x - mx.x); ex.y = __expf(e.y - mx.y);
        ex.z = __expf(e.z - mx.z); ex.w = __expf(e.w - mx.w);
        if (l < CAP) e4b[wv][l] = ex;
        sum.x += ex.x; sum.y += ex.y; sum.z += ex.z; sum.w += ex.w;
    }
#pragma unroll
    for (int o = 32; o; o >>= 1) {
        sum.x += __shfl_xor(sum.x, o);
        sum.y += __shfl_xor(sum.y, o);
        sum.z += __shfl_xor(sum.z, o);
        sum.w += __shfl_xor(sum.w, o);
    }
    float4 inv;
    inv.x = 1.0f / (sum.x + 1e-9f); inv.y = 1.0f / (sum.y + 1e-9f);
    inv.z = 1.0f / (sum.z + 1e-9f); inv.w = 1.0f / (sum.w + 1e-9f);

    // Phase C: alpha = ex * inv; write to output alpha; cache alpha in LDS
    for (int l = t; l < deg; l += 64) {
        float4 ex;
        if (l < CAP) ex = e4b[wv][l];
        else {
            int s = csr_src[beg + l];
            float4 ss = *(const float4*)(s_src + s * 4);
            float4 e;
            e.x = lrelu(ss.x + sd.x); e.y = lrelu(ss.y + sd.y);
            e.z = lrelu(ss.z + sd.z); e.w = lrelu(ss.w + sd.w);
            ex.x = __expf(e.x - mx.x); ex.y = __expf(e.y - mx.y);
            ex.z = __expf(e.z - mx.z); ex.w = __expf(e.w - mx.w);
        }
        float4 a;
        a.x = ex.x * inv.x; a.y = ex.y * inv.y;
        a.z = ex.z * inv.z; a.w = ex.w * inv.w;
        if (l < CAP) e4b[wv][l] = a;
        int eid = csr_eid[beg + l];
        *(float4*)(ebuf + (size_t)eid * 4) = a;
    }

    // Phase D: out[n, :] = sum_j alpha[j, h] * Wh[src_j, :]   (2 dims/lane)
    const int h = t >> 4;
    float2 acc = {0.0f, 0.0f};
    if (deg <= CAP) {
        int j = 0;
        for (; j + 1 < deg; j += 2) {
            int s0 = sbuf[wv][j], s1 = sbuf[wv][j + 1];
            float a0 = ((const float*)&e4b[wv][j])[h];
            float a1 = ((const float*)&e4b[wv][j + 1])[h];
            float2 w0 = *(const float2*)(Wh + (size_t)s0 * WH_DIM + 2 * t);
            float2 w1 = *(const float2*)(Wh + (size_t)s1 * WH_DIM + 2 * t);
            acc.x += a0 * w0.x + a1 * w1.x;
            acc.y += a0 * w0.y + a1 * w1.y;
        }
        if (j < deg) {
            int s0 = sbuf[wv][j];
            float a0 = ((const float*)&e4b[wv][j])[h];
            float2 w0 = *(const float2*)(Wh + (size_t)s0 * WH_DIM + 2 * t);
            acc.x += a0 * w0.x;
            acc.y += a0 * w0.y;
        }
    } else {
        float invh = (h == 0) ? inv.x : (h == 1) ? inv.y : (h == 2) ? inv.z : inv.w;
        float mxh  = (h == 0) ? mx.x  : (h == 1) ? mx.y  : (h == 2) ? mx.z  : mx.w;
        for (int j = 0; j < deg; ++j) {
            int s0;
            float a0;
            if (j < CAP) {
                s0 = sbuf[wv][j];
                a0 = ((const float*)&e4b[wv][j])[h];
            } else {
                s0 = csr_src[beg + j];
                float sh = s_src[s0 * 4 + h];
                float dh = (h == 0) ? sd.x : (h == 1) ? sd.y : (h == 2) ? sd.z : sd.w;
                a0 = __expf(lrelu(sh + dh) - mxh) * invh;
            }
            float2 w0 = *(const float2*)(Wh + (size_t)s0 * WH_DIM + 2 * t);
            acc.x += a0 * w0.x;
            acc.y += a0 * w0.y;
        }
    }
    *(float2*)(out_h + (size_t)n * WH_DIM + 2 * t) = acc;
}

// ---------------------------------------------------------------------------
extern "C" void kernel_launch(void* const* d_in, const int* in_sizes, int n_in,
                              void* d_out, int out_size, void* d_ws, size_t ws_size,
                              hipStream_t stream) {
    const float* x      = (const float*)d_in[0];
    const void*  eidx   = d_in[1];
    const float* weight = (const float*)d_in[2];
    const float* attn   = (const float*)d_in[3];

    float* out   = (float*)d_out;
    float* out_h = out;                                   // [N_NODES, 128]
    float* ebuf  = out + (size_t)N_NODES * WH_DIM;        // [N_EDGES, 4] alpha

    // workspace layout (16B-aligned chunks)
    char* ws = (char*)d_ws;
    int*   cnt     = (int*)ws;                            // [0, 200000)
    int*   flag    = (int*)(ws + 200000);                 // [200000, 200004)
    int*   woff    = (int*)(ws + 200016);                 // [200016, 400016)
    int*   off     = (int*)(ws + 400016);                 // [400016, 600020)
    int*   csr_src = (int*)(ws + 600032);                 // 6.4 MB
    int*   csr_eid = (int*)(ws + 7000032);                // 6.4 MB
    float* Wh      = (float*)(ws + 13400032);             // 25.6 MB
    float* s_src   = (float*)(ws + 39000032);             // 800 KB
    float* s_dst   = (float*)(ws + 39800032);             // 800 KB

    hipMemsetAsync(ws, 0, 200004, stream);                // cnt + flag

    k_detect<<<512, 256, 0, stream>>>((const int*)eidx, flag);
    k_wh<<<N_NODES / 4, 256, 0, stream>>>(x, weight, attn, Wh, s_src, s_dst);
    k_count<<<(N_EDGES + 255) / 256, 256, 0, stream>>>(eidx, flag, cnt);
    k_scan<<<1, 1024, 0, stream>>>(cnt, off, woff);
    k_scatter<<<(N_EDGES + 255) / 256, 256, 0, stream>>>(eidx, flag, woff,
                                                         csr_src, csr_eid);
    k_node<<<N_NODES / 4, 256, 0, stream>>>(off, csr_src, csr_eid,
                                            s_src, s_dst, Wh, ebuf, out_h);
}

// Round 3
// 459.396 us; speedup vs baseline: 3.4071x; 1.5408x over previous
//
#include <hip/hip_runtime.h>
#include <hip/hip_bf16.h>
#include <math.h>

#define N_NODES 50000
#define N_EDGES 1600000
#define IN_DIM  128
#define OUT_DIM 32
#define N_HEADS 4
#define WH_DIM  (N_HEADS * OUT_DIM)   // 128
#define CAP     128                   // per-node LDS edge cache (max deg ~58)
#define NB_SCAN 196                   // ceil(50000/256)

// ---------------------------------------------------------------------------
// edge_index may arrive as int32 or int64. For int64, odd 32-bit words are
// all-zero hi-words; for int32 they are dst values (random, mostly nonzero).
// Sample 256 odd words spread across the array.
// ---------------------------------------------------------------------------
__device__ __forceinline__ void load_edge(const void* eidx, int is32, int e,
                                          int& s, int& d) {
    if (is32) {
        const int2 v = ((const int2*)eidx)[e];
        s = v.x; d = v.y;
    } else {
        const longlong2 v = ((const longlong2*)eidx)[e];
        s = (int)v.x; d = (int)v.y;
    }
}

__global__ void k_detect(const int* __restrict__ eidx, int* __restrict__ flag) {
    int i = threadIdx.x;                       // 256 threads, 1 block
    int r = eidx[2 * (i * (N_EDGES / 256)) + 1];
    if (r != 0) atomicOr(flag, 1);             // nonzero hi-word => int32
}

// ---------------------------------------------------------------------------
// Tiled f32 GEMM: Wh16[n, h*32+o] = bf16( sum_i x[n,i] * weight[h,i,o] )
// plus fused attention dots s_src/s_dst (f32, from f32 accumulators).
// Block: 256 threads, 64 nodes x 128 cols; thread = (node-group of 16) x (col pair).
// ---------------------------------------------------------------------------
#define WB_K 32
__global__ __launch_bounds__(256) void k_wh(
        const float* __restrict__ x, const float* __restrict__ weight,
        const float* __restrict__ attn,
        __hip_bfloat16* __restrict__ Wh16,
        float* __restrict__ s_src, float* __restrict__ s_dst) {
    __shared__ float xs[64 * WB_K];      // [n][k] stride 32, 8 KB
    __shared__ float wsm[WB_K * 128];    // [k][c], 16 KB
    const int t  = threadIdx.x;
    const int nb = blockIdx.x * 64;
    const int ng = t >> 6;               // node group (16 nodes), == wave id
    const int cp = t & 63;               // col pair: cols 2cp, 2cp+1
    const int c0 = 2 * cp;

    float2 acc[16];
#pragma unroll
    for (int j = 0; j < 16; ++j) acc[j] = make_float2(0.f, 0.f);

    for (int k0 = 0; k0 < IN_DIM; k0 += WB_K) {
        __syncthreads();
        // x tile: 64 nodes x 32 k = 512 float4, 2 per thread (clamped rows)
#pragma unroll
        for (int r = 0; r < 2; ++r) {
            int f = t + r * 256;
            int n = f >> 3;
            int i4 = (f & 7) * 4;
            int ngl = nb + n; if (ngl > N_NODES - 1) ngl = N_NODES - 1;
            float4 v = *(const float4*)(x + (size_t)ngl * IN_DIM + k0 + i4);
            *(float4*)(xs + n * WB_K + i4) = v;
        }
        // w tile: 32 k x 128 c = 1024 float4, 4 per thread
#pragma unroll
        for (int r = 0; r < 4; ++r) {
            int f = t + r * 256;
            int i = f >> 5;
            int c = (f & 31) * 4;
            int h = c >> 5, o = c & 31;
            float4 v = *(const float4*)(weight + h * (IN_DIM * OUT_DIM)
                                        + (size_t)(k0 + i) * OUT_DIM + o);
            *(float4*)(wsm + i * 128 + c) = v;
        }
        __syncthreads();

        const float* xrow = xs + ng * 16 * WB_K;
#pragma unroll
        for (int i = 0; i < WB_K; i += 4) {
            float2 w0 = *(const float2*)(wsm + (i + 0) * 128 + c0);
            float2 w1 = *(const float2*)(wsm + (i + 1) * 128 + c0);
            float2 w2 = *(const float2*)(wsm + (i + 2) * 128 + c0);
            float2 w3 = *(const float2*)(wsm + (i + 3) * 128 + c0);
#pragma unroll
            for (int j = 0; j < 16; ++j) {
                float4 xv = *(const float4*)(xrow + j * WB_K + i);  // broadcast
                acc[j].x += xv.x * w0.x + xv.y * w1.x + xv.z * w2.x + xv.w * w3.x;
                acc[j].y += xv.x * w0.y + xv.y * w1.y + xv.z * w2.y + xv.w * w3.y;
            }
        }
    }

    // epilogue: bf16 store + fused attention dots
    const int h = c0 >> 5;
    const int o = c0 & 31;
    const float as0 = attn[h * 64 + o],      as1 = attn[h * 64 + o + 1];
    const float ad0 = attn[h * 64 + 32 + o], ad1 = attn[h * 64 + 32 + o + 1];
#pragma unroll
    for (int j = 0; j < 16; ++j) {
        const int n = nb + ng * 16 + j;
        const bool ok = n < N_NODES;
        if (ok) {
            __hip_bfloat162 hv = __float22bfloat162_rn(acc[j]);
            *(__hip_bfloat162*)(Wh16 + (size_t)n * WH_DIM + c0) = hv;
        }
        float vs = acc[j].x * as0 + acc[j].y * as1;
        float vd = acc[j].x * ad0 + acc[j].y * ad1;
#pragma unroll
        for (int off2 = 8; off2; off2 >>= 1) {   // reduce over 16-lane head group
            vs += __shfl_xor(vs, off2);
            vd += __shfl_xor(vd, off2);
        }
        if (ok && (cp & 15) == j) {
            s_src[n * N_HEADS + h] = vs;
            s_dst[n * N_HEADS + h] = vd;
        }
    }
}

// ---------------------------------------------------------------------------
// CSR build: count -> 3-phase parallel scan -> scatter (packed int2{src,eid})
// ---------------------------------------------------------------------------
__global__ __launch_bounds__(256) void k_count(
        const void* __restrict__ eidx, const int* __restrict__ flag,
        int* __restrict__ cnt) {
    int e = blockIdx.x * 256 + threadIdx.x;
    if (e >= N_EDGES) return;
    int s, d;
    load_edge(eidx, *flag, e, s, d);
    atomicAdd(cnt + d, 1);
}

__global__ __launch_bounds__(256) void k_scan1(
        const int* __restrict__ cnt, int* __restrict__ pre,
        int* __restrict__ bsum) {
    __shared__ int sh[256];
    const int t = threadIdx.x;
    const int i = blockIdx.x * 256 + t;
    int v = (i < N_NODES) ? cnt[i] : 0;
    sh[t] = v;
    __syncthreads();
    for (int d = 1; d < 256; d <<= 1) {
        int u = (t >= d) ? sh[t - d] : 0;
        __syncthreads();
        sh[t] += u;
        __syncthreads();
    }
    if (i < N_NODES) pre[i] = sh[t] - v;
    if (t == 255) bsum[blockIdx.x] = sh[255];
}

__global__ __launch_bounds__(256) void k_scan2(
        const int* __restrict__ bsum, int* __restrict__ bbase,
        int* __restrict__ off_last) {
    __shared__ int sh[256];
    const int t = threadIdx.x;
    int v = (t < NB_SCAN) ? bsum[t] : 0;
    sh[t] = v;
    __syncthreads();
    for (int d = 1; d < 256; d <<= 1) {
        int u = (t >= d) ? sh[t - d] : 0;
        __syncthreads();
        sh[t] += u;
        __syncthreads();
    }
    if (t < NB_SCAN) bbase[t] = sh[t] - v;
    if (t == 255) *off_last = sh[255];           // == N_EDGES
}

__global__ __launch_bounds__(256) void k_scan3(
        const int* __restrict__ pre, const int* __restrict__ bbase,
        int* __restrict__ off, int* __restrict__ woff) {
    int i = blockIdx.x * 256 + threadIdx.x;
    if (i >= N_NODES) return;
    int o = pre[i] + bbase[blockIdx.x];
    off[i] = o;
    woff[i] = o;
}

__global__ __launch_bounds__(256) void k_scatter(
        const void* __restrict__ eidx, const int* __restrict__ flag,
        int* __restrict__ woff, int2* __restrict__ csr) {
    int e = blockIdx.x * 256 + threadIdx.x;
    if (e >= N_EDGES) return;
    int s, d;
    load_edge(eidx, *flag, e, s, d);
    int pos = atomicAdd(woff + d, 1);
    csr[pos] = make_int2(s, e);
}

// ---------------------------------------------------------------------------
// One wave per dst node: segment softmax + weighted accumulate (bf16 Wh gather)
// ---------------------------------------------------------------------------
__device__ __forceinline__ float lrelu(float v) {
    return v > 0.0f ? v : 0.2f * v;
}

__global__ __launch_bounds__(256) void k_node(
        const int* __restrict__ off, const int2* __restrict__ csr,
        const float* __restrict__ s_src, const float* __restrict__ s_dst,
        const __hip_bfloat16* __restrict__ Wh16,
        float* __restrict__ ebuf, float* __restrict__ out_h) {
    __shared__ int2   sbuf[4][CAP];                     // {src, eid}
    __shared__ float4 e4b[4][CAP];                      // e -> ex -> alpha
    const int wv = threadIdx.x >> 6;
    const int t  = threadIdx.x & 63;
    const int n  = blockIdx.x * 4 + wv;
    const int beg = off[n], end = off[n + 1], deg = end - beg;

    const float4 sd = *(const float4*)(s_dst + n * 4);

    // Phase A: e = leaky_relu(s_src[src] + s_dst[n]); cache; running max
    float4 mx = {-INFINITY, -INFINITY, -INFINITY, -INFINITY};
    for (int l = t; l < deg; l += 64) {
        int2 se = csr[beg + l];
        float4 ss = *(const float4*)(s_src + se.x * 4);
        float4 e;
        e.x = lrelu(ss.x + sd.x); e.y = lrelu(ss.y + sd.y);
        e.z = lrelu(ss.z + sd.z); e.w = lrelu(ss.w + sd.w);
        if (l < CAP) { sbuf[wv][l] = se; e4b[wv][l] = e; }
        mx.x = fmaxf(mx.x, e.x); mx.y = fmaxf(mx.y, e.y);
        mx.z = fmaxf(mx.z, e.z); mx.w = fmaxf(mx.w, e.w);
    }
#pragma unroll
    for (int o = 32; o; o >>= 1) {
        mx.x = fmaxf(mx.x, __shfl_xor(mx.x, o));
        mx.y = fmaxf(mx.y, __shfl_xor(mx.y, o));
        mx.z = fmaxf(mx.z, __shfl_xor(mx.z, o));
        mx.w = fmaxf(mx.w, __shfl_xor(mx.w, o));
    }

    // Phase B: ex = exp(e - mx); cache; running sum
    float4 sum = {0.0f, 0.0f, 0.0f, 0.0f};
    for (int l = t; l < deg; l += 64) {
        float4 e;
        if (l < CAP) e = e4b[wv][l];
        else {
            int2 se = csr[beg + l];
            float4 ss = *(const float4*)(s_src + se.x * 4);
            e.x = lrelu(ss.x + sd.x); e.y = lrelu(ss.y + sd.y);
            e.z = lrelu(ss.z + sd.z); e.w = lrelu(ss.w + sd.w);
        }
        float4 ex;
        ex.x = __expf(e.x - mx.x); ex.y = __expf(e.y - mx.y);
        ex.z = __expf(e.z - mx.z); ex.w = __expf(e.w - mx.w);
        if (l < CAP) e4b[wv][l] = ex;
        sum.x += ex.x; sum.y += ex.y; sum.z += ex.z; sum.w += ex.w;
    }
#pragma unroll
    for (int o = 32; o; o >>= 1) {
        sum.x += __shfl_xor(sum.x, o);
        sum.y += __shfl_xor(sum.y, o);
        sum.z += __shfl_xor(sum.z, o);
        sum.w += __shfl_xor(sum.w, o);
    }
    float4 inv;
    inv.x = 1.0f / (sum.x + 1e-9f); inv.y = 1.0f / (sum.y + 1e-9f);
    inv.z = 1.0f / (sum.z + 1e-9f); inv.w = 1.0f / (sum.w + 1e-9f);

    // Phase C: alpha = ex * inv; write to output alpha region; cache in LDS
    for (int l = t; l < deg; l += 64) {
        float4 ex; int eid;
        if (l < CAP) { ex = e4b[wv][l]; eid = sbuf[wv][l].y; }
        else {
            int2 se = csr[beg + l];
            eid = se.y;
            float4 ss = *(const float4*)(s_src + se.x * 4);
            float4 e;
            e.x = lrelu(ss.x + sd.x); e.y = lrelu(ss.y + sd.y);
            e.z = lrelu(ss.z + sd.z); e.w = lrelu(ss.w + sd.w);
            ex.x = __expf(e.x - mx.x); ex.y = __expf(e.y - mx.y);
            ex.z = __expf(e.z - mx.z); ex.w = __expf(e.w - mx.w);
        }
        float4 a;
        a.x = ex.x * inv.x; a.y = ex.y * inv.y;
        a.z = ex.z * inv.z; a.w = ex.w * inv.w;
        if (l < CAP) e4b[wv][l] = a;
        *(float4*)(ebuf + (size_t)eid * 4) = a;
    }

    // Phase D: out[n, :] = sum_j alpha[j, h] * Wh16[src_j, :]  (2 cols/lane)
    const int h = t >> 4;
    float2 acc = {0.0f, 0.0f};
    if (deg <= CAP) {
        int j = 0;
        for (; j + 1 < deg; j += 2) {
            int s0 = sbuf[wv][j].x, s1 = sbuf[wv][j + 1].x;
            float a0 = ((const float*)&e4b[wv][j])[h];
            float a1 = ((const float*)&e4b[wv][j + 1])[h];
            __hip_bfloat162 w0 = ((const __hip_bfloat162*)(Wh16 + (size_t)s0 * WH_DIM))[t];
            __hip_bfloat162 w1 = ((const __hip_bfloat162*)(Wh16 + (size_t)s1 * WH_DIM))[t];
            float2 f0 = __bfloat1622float2(w0);
            float2 f1 = __bfloat1622float2(w1);
            acc.x += a0 * f0.x + a1 * f1.x;
            acc.y += a0 * f0.y + a1 * f1.y;
        }
        if (j < deg) {
            int s0 = sbuf[wv][j].x;
            float a0 = ((const float*)&e4b[wv][j])[h];
            __hip_bfloat162 w0 = ((const __hip_bfloat162*)(Wh16 + (size_t)s0 * WH_DIM))[t];
            float2 f0 = __bfloat1622float2(w0);
            acc.x += a0 * f0.x;
            acc.y += a0 * f0.y;
        }
    } else {
        float invh = (h == 0) ? inv.x : (h == 1) ? inv.y : (h == 2) ? inv.z : inv.w;
        float mxh  = (h == 0) ? mx.x  : (h == 1) ? mx.y  : (h == 2) ? mx.z  : mx.w;
        for (int j = 0; j < deg; ++j) {
            int s0; float a0;
            if (j < CAP) {
                s0 = sbuf[wv][j].x;
                a0 = ((const float*)&e4b[wv][j])[h];
            } else {
                s0 = csr[beg + j].x;
                float sh = s_src[s0 * 4 + h];
                float dh = (h == 0) ? sd.x : (h == 1) ? sd.y : (h == 2) ? sd.z : sd.w;
                a0 = __expf(lrelu(sh + dh) - mxh) * invh;
            }
            __hip_bfloat162 w0 = ((const __hip_bfloat162*)(Wh16 + (size_t)s0 * WH_DIM))[t];
            float2 f0 = __bfloat1622float2(w0);
            acc.x += a0 * f0.x;
            acc.y += a0 * f0.y;
        }
    }
    *(float2*)(out_h + (size_t)n * WH_DIM + 2 * t) = acc;
}

// ---------------------------------------------------------------------------
extern "C" void kernel_launch(void* const* d_in, const int* in_sizes, int n_in,
                              void* d_out, int out_size, void* d_ws, size_t ws_size,
                              hipStream_t stream) {
    const float* x      = (const float*)d_in[0];
    const void*  eidx   = d_in[1];
    const float* weight = (const float*)d_in[2];
    const float* attn   = (const float*)d_in[3];

    float* out   = (float*)d_out;
    float* out_h = out;                                   // [N_NODES, 128]
    float* ebuf  = out + (size_t)N_NODES * WH_DIM;        // [N_EDGES, 4] alpha

    // workspace layout (64-B aligned chunks)
    char* ws = (char*)d_ws;
    int*   cnt   = (int*)ws;                              // 200000 B
    int*   flag  = (int*)(ws + 200064);
    int*   woff  = (int*)(ws + 200128);                   // 200000 B
    int*   off   = (int*)(ws + 400192);                   // 200004 B
    int*   pre   = (int*)(ws + 600256);                   // 200000 B
    int*   bsum  = (int*)(ws + 800320);                   // 784 B
    int*   bbase = (int*)(ws + 801152);                   // 784 B
    int2*  csr   = (int2*)(ws + 802048);                  // 12.8 MB
    __hip_bfloat16* Wh16 = (__hip_bfloat16*)(ws + 13602048);  // 12.8 MB
    float* s_src = (float*)(ws + 26402048);               // 800 KB
    float* s_dst = (float*)(ws + 27202048);               // 800 KB

    hipMemsetAsync(ws, 0, 200068, stream);                // cnt + flag

    k_detect<<<1, 256, 0, stream>>>((const int*)eidx, flag);
    k_wh<<<(N_NODES + 63) / 64, 256, 0, stream>>>(x, weight, attn,
                                                  Wh16, s_src, s_dst);
    k_count<<<(N_EDGES + 255) / 256, 256, 0, stream>>>(eidx, flag, cnt);
    k_scan1<<<NB_SCAN, 256, 0, stream>>>(cnt, pre, bsum);
    k_scan2<<<1, 256, 0, stream>>>(bsum, bbase, off + N_NODES);
    k_scan3<<<NB_SCAN, 256, 0, stream>>>(pre, bbase, off, woff);
    k_scatter<<<(N_EDGES + 255) / 256, 256, 0, stream>>>(eidx, flag, woff, csr);
    k_node<<<N_NODES / 4, 256, 0, stream>>>(off, csr, s_src, s_dst,
                                            Wh16, ebuf, out_h);
}

// Round 4
// 380.481 us; speedup vs baseline: 4.1137x; 1.2074x over previous
//
#include <hip/hip_runtime.h>
#include <hip/hip_bf16.h>
#include <math.h>

#define N_NODES 50000
#define N_EDGES 1600000
#define IN_DIM  128
#define OUT_DIM 32
#define N_HEADS 4
#define WH_DIM  (N_HEADS * OUT_DIM)   // 128
#define CAP     128                   // per-node LDS edge cache (max deg ~58)
#define NB_SCAN 196                   // ceil(50000/256)
#define NPASS   4                     // scatter dst-windows
#define WIN     ((N_NODES + NPASS - 1) / NPASS)   // 12500

// ---------------------------------------------------------------------------
// edge_index may arrive as int32 or int64. For int64, odd 32-bit words are
// all-zero hi-words; for int32 they are dst values (random, mostly nonzero).
// ---------------------------------------------------------------------------
__device__ __forceinline__ void load_edge(const void* eidx, int is32, int e,
                                          int& s, int& d) {
    if (is32) {
        const int2 v = ((const int2*)eidx)[e];
        s = v.x; d = v.y;
    } else {
        const longlong2 v = ((const longlong2*)eidx)[e];
        s = (int)v.x; d = (int)v.y;
    }
}

__global__ void k_detect(const int* __restrict__ eidx, int* __restrict__ flag) {
    int i = threadIdx.x;                       // 256 threads, 1 block
    int r = eidx[2 * (i * (N_EDGES / 256)) + 1];
    if (r != 0) atomicOr(flag, 1);             // nonzero hi-word => int32
}

// ---------------------------------------------------------------------------
// Tiled f32 GEMM: Wh16[n, h*32+o] = bf16( sum_i x[n,i] * weight[h,i,o] )
// plus fused attention dots s_src/s_dst (f32, from f32 accumulators).
// ---------------------------------------------------------------------------
#define WB_K 32
__global__ __launch_bounds__(256) void k_wh(
        const float* __restrict__ x, const float* __restrict__ weight,
        const float* __restrict__ attn,
        __hip_bfloat16* __restrict__ Wh16,
        float* __restrict__ s_src, float* __restrict__ s_dst) {
    __shared__ float xs[64 * WB_K];      // 8 KB
    __shared__ float wsm[WB_K * 128];    // 16 KB
    const int t  = threadIdx.x;
    const int nb = blockIdx.x * 64;
    const int ng = t >> 6;               // node group (16 nodes), == wave id
    const int cp = t & 63;               // col pair
    const int c0 = 2 * cp;

    float2 acc[16];
#pragma unroll
    for (int j = 0; j < 16; ++j) acc[j] = make_float2(0.f, 0.f);

    for (int k0 = 0; k0 < IN_DIM; k0 += WB_K) {
        __syncthreads();
#pragma unroll
        for (int r = 0; r < 2; ++r) {
            int f = t + r * 256;
            int n = f >> 3;
            int i4 = (f & 7) * 4;
            int ngl = nb + n; if (ngl > N_NODES - 1) ngl = N_NODES - 1;
            float4 v = *(const float4*)(x + (size_t)ngl * IN_DIM + k0 + i4);
            *(float4*)(xs + n * WB_K + i4) = v;
        }
#pragma unroll
        for (int r = 0; r < 4; ++r) {
            int f = t + r * 256;
            int i = f >> 5;
            int c = (f & 31) * 4;
            int h = c >> 5, o = c & 31;
            float4 v = *(const float4*)(weight + h * (IN_DIM * OUT_DIM)
                                        + (size_t)(k0 + i) * OUT_DIM + o);
            *(float4*)(wsm + i * 128 + c) = v;
        }
        __syncthreads();

        const float* xrow = xs + ng * 16 * WB_K;
#pragma unroll
        for (int i = 0; i < WB_K; i += 4) {
            float2 w0 = *(const float2*)(wsm + (i + 0) * 128 + c0);
            float2 w1 = *(const float2*)(wsm + (i + 1) * 128 + c0);
            float2 w2 = *(const float2*)(wsm + (i + 2) * 128 + c0);
            float2 w3 = *(const float2*)(wsm + (i + 3) * 128 + c0);
#pragma unroll
            for (int j = 0; j < 16; ++j) {
                float4 xv = *(const float4*)(xrow + j * WB_K + i);  // broadcast
                acc[j].x += xv.x * w0.x + xv.y * w1.x + xv.z * w2.x + xv.w * w3.x;
                acc[j].y += xv.x * w0.y + xv.y * w1.y + xv.z * w2.y + xv.w * w3.y;
            }
        }
    }

    const int h = c0 >> 5;
    const int o = c0 & 31;
    const float as0 = attn[h * 64 + o],      as1 = attn[h * 64 + o + 1];
    const float ad0 = attn[h * 64 + 32 + o], ad1 = attn[h * 64 + 32 + o + 1];
#pragma unroll
    for (int j = 0; j < 16; ++j) {
        const int n = nb + ng * 16 + j;
        const bool ok = n < N_NODES;
        if (ok) {
            __hip_bfloat162 hv = __float22bfloat162_rn(acc[j]);
            *(__hip_bfloat162*)(Wh16 + (size_t)n * WH_DIM + c0) = hv;
        }
        float vs = acc[j].x * as0 + acc[j].y * as1;
        float vd = acc[j].x * ad0 + acc[j].y * ad1;
#pragma unroll
        for (int off2 = 8; off2; off2 >>= 1) {
            vs += __shfl_xor(vs, off2);
            vd += __shfl_xor(vd, off2);
        }
        if (ok && (cp & 15) == j) {
            s_src[n * N_HEADS + h] = vs;
            s_dst[n * N_HEADS + h] = vd;
        }
    }
}

// ---------------------------------------------------------------------------
// k_prep: canonicalize edges to int32 SoA + per-edge rank within dst segment
// ---------------------------------------------------------------------------
__global__ __launch_bounds__(256) void k_prep(
        const void* __restrict__ eidx, const int* __restrict__ flag,
        int* __restrict__ s32, int* __restrict__ d32,
        int* __restrict__ rank, int* __restrict__ cnt) {
    int e = blockIdx.x * 256 + threadIdx.x;
    if (e >= N_EDGES) return;
    int s, d;
    load_edge(eidx, *flag, e, s, d);
    s32[e] = s;
    d32[e] = d;
    rank[e] = atomicAdd(cnt + d, 1);
}

// ---------------------------------------------------------------------------
// 3-phase parallel exclusive scan of cnt -> off
// ---------------------------------------------------------------------------
__global__ __launch_bounds__(256) void k_scan1(
        const int* __restrict__ cnt, int* __restrict__ pre,
        int* __restrict__ bsum) {
    __shared__ int sh[256];
    const int t = threadIdx.x;
    const int i = blockIdx.x * 256 + t;
    int v = (i < N_NODES) ? cnt[i] : 0;
    sh[t] = v;
    __syncthreads();
    for (int d = 1; d < 256; d <<= 1) {
        int u = (t >= d) ? sh[t - d] : 0;
        __syncthreads();
        sh[t] += u;
        __syncthreads();
    }
    if (i < N_NODES) pre[i] = sh[t] - v;
    if (t == 255) bsum[blockIdx.x] = sh[255];
}

__global__ __launch_bounds__(256) void k_scan2(
        const int* __restrict__ bsum, int* __restrict__ bbase,
        int* __restrict__ off_last) {
    __shared__ int sh[256];
    const int t = threadIdx.x;
    int v = (t < NB_SCAN) ? bsum[t] : 0;
    sh[t] = v;
    __syncthreads();
    for (int d = 1; d < 256; d <<= 1) {
        int u = (t >= d) ? sh[t - d] : 0;
        __syncthreads();
        sh[t] += u;
        __syncthreads();
    }
    if (t < NB_SCAN) bbase[t] = sh[t] - v;
    if (t == 255) *off_last = sh[255];           // == N_EDGES
}

__global__ __launch_bounds__(256) void k_scan3(
        const int* __restrict__ pre, const int* __restrict__ bbase,
        int* __restrict__ off) {
    int i = blockIdx.x * 256 + threadIdx.x;
    if (i >= N_NODES) return;
    off[i] = pre[i] + bbase[blockIdx.x];
}

// ---------------------------------------------------------------------------
// Windowed atomic-free scatter: pass y handles dst in [y*WIN, (y+1)*WIN).
// Store region per pass ~1.6 MB -> L2-resident, no write amplification.
// ---------------------------------------------------------------------------
__global__ __launch_bounds__(256) void k_scatter(
        const int* __restrict__ s32, const int* __restrict__ d32,
        const int* __restrict__ rank, const int* __restrict__ off,
        int* __restrict__ csr) {
    int e = blockIdx.x * 256 + threadIdx.x;
    if (e >= N_EDGES) return;
    int d = d32[e];
    if ((unsigned)(d - blockIdx.y * WIN) >= WIN) return;
    csr[off[d] + rank[e]] = s32[e];
}

// ---------------------------------------------------------------------------
// One wave per dst node: segment softmax stats + weighted accumulate.
// Writes out_h (coalesced) and per-node mx/inv for k_alpha.
// ---------------------------------------------------------------------------
__device__ __forceinline__ float lrelu(float v) {
    return v > 0.0f ? v : 0.2f * v;
}

__global__ __launch_bounds__(256) void k_node(
        const int* __restrict__ off, const int* __restrict__ csr,
        const float* __restrict__ s_src, const float* __restrict__ s_dst,
        const __hip_bfloat16* __restrict__ Wh16,
        float* __restrict__ mxb, float* __restrict__ invb,
        float* __restrict__ out_h) {
    __shared__ int    sbuf[4][CAP];
    __shared__ float4 e4b[4][CAP];                      // ex values
    const int wv = threadIdx.x >> 6;
    const int t  = threadIdx.x & 63;
    const int n  = blockIdx.x * 4 + wv;
    const int beg = off[n], end = off[n + 1], deg = end - beg;

    const float4 sd = *(const float4*)(s_dst + n * 4);

    // Phase A: e = lrelu(s_src[src] + s_dst[n]); cache e; running max
    float4 mx = {-INFINITY, -INFINITY, -INFINITY, -INFINITY};
    for (int l = t; l < deg; l += 64) {
        int s = csr[beg + l];
        float4 ss = *(const float4*)(s_src + s * 4);
        float4 e;
        e.x = lrelu(ss.x + sd.x); e.y = lrelu(ss.y + sd.y);
        e.z = lrelu(ss.z + sd.z); e.w = lrelu(ss.w + sd.w);
        if (l < CAP) { sbuf[wv][l] = s; e4b[wv][l] = e; }
        mx.x = fmaxf(mx.x, e.x); mx.y = fmaxf(mx.y, e.y);
        mx.z = fmaxf(mx.z, e.z); mx.w = fmaxf(mx.w, e.w);
    }
#pragma unroll
    for (int o = 32; o; o >>= 1) {
        mx.x = fmaxf(mx.x, __shfl_xor(mx.x, o));
        mx.y = fmaxf(mx.y, __shfl_xor(mx.y, o));
        mx.z = fmaxf(mx.z, __shfl_xor(mx.z, o));
        mx.w = fmaxf(mx.w, __shfl_xor(mx.w, o));
    }

    // Phase B: ex = exp(e - mx); cache; running sum
    float4 sum = {0.0f, 0.0f, 0.0f, 0.0f};
    for (int l = t; l < deg; l += 64) {
        float4 e;
        if (l < CAP) e = e4b[wv][l];
        else {
            int s = csr[beg + l];
            float4 ss = *(const float4*)(s_src + s * 4);
            e.x = lrelu(ss.x + sd.x); e.y = lrelu(ss.y + sd.y);
            e.z = lrelu(ss.z + sd.z); e.w = lrelu(ss.w + sd.w);
        }
        float4 ex;
        ex.x = __expf(e.x - mx.x); ex.y = __expf(e.y - mx.y);
        ex.z = __expf(e.z - mx.z); ex.w = __expf(e.w - mx.w);
        if (l < CAP) e4b[wv][l] = ex;
        sum.x += ex.x; sum.y += ex.y; sum.z += ex.z; sum.w += ex.w;
    }
#pragma unroll
    for (int o = 32; o; o >>= 1) {
        sum.x += __shfl_xor(sum.x, o);
        sum.y += __shfl_xor(sum.y, o);
        sum.z += __shfl_xor(sum.z, o);
        sum.w += __shfl_xor(sum.w, o);
    }
    float4 inv;
    inv.x = 1.0f / (sum.x + 1e-9f); inv.y = 1.0f / (sum.y + 1e-9f);
    inv.z = 1.0f / (sum.z + 1e-9f); inv.w = 1.0f / (sum.w + 1e-9f);

    if (t == 0) {
        *(float4*)(mxb  + n * 4) = mx;
        *(float4*)(invb + n * 4) = inv;
    }

    // Phase D: out[n, :] = sum_j (ex_j[h]*inv[h]) * Wh16[src_j, :]
    const int h = t >> 4;
    const float invh = (h == 0) ? inv.x : (h == 1) ? inv.y
                     : (h == 2) ? inv.z : inv.w;
    float2 acc = {0.0f, 0.0f};
    if (deg <= CAP) {
        int j = 0;
        for (; j + 3 < deg; j += 4) {
            int s0 = sbuf[wv][j],     s1 = sbuf[wv][j + 1];
            int s2 = sbuf[wv][j + 2], s3 = sbuf[wv][j + 3];
            float a0 = ((const float*)&e4b[wv][j])[h]     * invh;
            float a1 = ((const float*)&e4b[wv][j + 1])[h] * invh;
            float a2 = ((const float*)&e4b[wv][j + 2])[h] * invh;
            float a3 = ((const float*)&e4b[wv][j + 3])[h] * invh;
            __hip_bfloat162 w0 = ((const __hip_bfloat162*)(Wh16 + (size_t)s0 * WH_DIM))[t];
            __hip_bfloat162 w1 = ((const __hip_bfloat162*)(Wh16 + (size_t)s1 * WH_DIM))[t];
            __hip_bfloat162 w2 = ((const __hip_bfloat162*)(Wh16 + (size_t)s2 * WH_DIM))[t];
            __hip_bfloat162 w3 = ((const __hip_bfloat162*)(Wh16 + (size_t)s3 * WH_DIM))[t];
            float2 f0 = __bfloat1622float2(w0);
            float2 f1 = __bfloat1622float2(w1);
            float2 f2 = __bfloat1622float2(w2);
            float2 f3 = __bfloat1622float2(w3);
            acc.x += a0 * f0.x + a1 * f1.x + a2 * f2.x + a3 * f3.x;
            acc.y += a0 * f0.y + a1 * f1.y + a2 * f2.y + a3 * f3.y;
        }
        for (; j < deg; ++j) {
            int s0 = sbuf[wv][j];
            float a0 = ((const float*)&e4b[wv][j])[h] * invh;
            __hip_bfloat162 w0 = ((const __hip_bfloat162*)(Wh16 + (size_t)s0 * WH_DIM))[t];
            float2 f0 = __bfloat1622float2(w0);
            acc.x += a0 * f0.x;
            acc.y += a0 * f0.y;
        }
    } else {
        float mxh = (h == 0) ? mx.x : (h == 1) ? mx.y : (h == 2) ? mx.z : mx.w;
        float dh  = (h == 0) ? sd.x : (h == 1) ? sd.y : (h == 2) ? sd.z : sd.w;
        for (int j = 0; j < deg; ++j) {
            int s0; float a0;
            if (j < CAP) {
                s0 = sbuf[wv][j];
                a0 = ((const float*)&e4b[wv][j])[h] * invh;
            } else {
                s0 = csr[beg + j];
                float sh = s_src[s0 * 4 + h];
                a0 = __expf(lrelu(sh + dh) - mxh) * invh;
            }
            __hip_bfloat162 w0 = ((const __hip_bfloat162*)(Wh16 + (size_t)s0 * WH_DIM))[t];
            float2 f0 = __bfloat1622float2(w0);
            acc.x += a0 * f0.x;
            acc.y += a0 * f0.y;
        }
    }
    *(float2*)(out_h + (size_t)n * WH_DIM + 2 * t) = acc;
}

// ---------------------------------------------------------------------------
// Edge-parallel alpha: coalesced read of edges, coalesced float4 write.
// ---------------------------------------------------------------------------
__global__ __launch_bounds__(256) void k_alpha(
        const int* __restrict__ s32, const int* __restrict__ d32,
        const float* __restrict__ s_src, const float* __restrict__ s_dst,
        const float* __restrict__ mxb, const float* __restrict__ invb,
        float* __restrict__ ebuf) {
    int e = blockIdx.x * 256 + threadIdx.x;
    if (e >= N_EDGES) return;
    int s = s32[e], d = d32[e];
    float4 ss = *(const float4*)(s_src + s * 4);
    float4 sd = *(const float4*)(s_dst + d * 4);
    float4 m  = *(const float4*)(mxb + d * 4);
    float4 iv = *(const float4*)(invb + d * 4);
    float4 a;
    a.x = __expf(lrelu(ss.x + sd.x) - m.x) * iv.x;
    a.y = __expf(lrelu(ss.y + sd.y) - m.y) * iv.y;
    a.z = __expf(lrelu(ss.z + sd.z) - m.z) * iv.z;
    a.w = __expf(lrelu(ss.w + sd.w) - m.w) * iv.w;
    *(float4*)(ebuf + (size_t)e * 4) = a;
}

// ---------------------------------------------------------------------------
extern "C" void kernel_launch(void* const* d_in, const int* in_sizes, int n_in,
                              void* d_out, int out_size, void* d_ws, size_t ws_size,
                              hipStream_t stream) {
    const float* x      = (const float*)d_in[0];
    const void*  eidx   = d_in[1];
    const float* weight = (const float*)d_in[2];
    const float* attn   = (const float*)d_in[3];

    float* out   = (float*)d_out;
    float* out_h = out;                                   // [N_NODES, 128]
    float* ebuf  = out + (size_t)N_NODES * WH_DIM;        // [N_EDGES, 4] alpha

    // workspace layout (64-B aligned); total ~40.4 MB
    char* ws = (char*)d_ws;
    int*   cnt   = (int*)ws;                              // 200000 B
    int*   flag  = (int*)(ws + 200064);
    int*   off   = (int*)(ws + 200128);                   // 200004 B
    int*   bsum  = (int*)(ws + 400192);                   // 784 B
    int*   bbase = (int*)(ws + 401024);                   // 784 B
    int*   s32   = (int*)(ws + 401856);                   // 6.4 MB
    int*   d32   = (int*)(ws + 6801856);                  // 6.4 MB
    int*   rank  = (int*)(ws + 13201856);                 // 6.4 MB
    int*   csr   = (int*)(ws + 19601856);                 // 6.4 MB
    int*   pre   = csr;                                   // aliases csr (dead before scatter)
    __hip_bfloat16* Wh16 = (__hip_bfloat16*)(ws + 26001856);  // 12.8 MB
    float* s_src = (float*)(ws + 38801856);               // 800 KB
    float* s_dst = (float*)(ws + 39601856);               // 800 KB
    float* mxb   = (float*)(ws + 13201856);               // aliases rank (dead after scatter)
    float* invb  = (float*)(ws + 13201856 + 800000);

    hipMemsetAsync(ws, 0, 200068, stream);                // cnt + flag

    k_detect<<<1, 256, 0, stream>>>((const int*)eidx, flag);
    k_wh<<<(N_NODES + 63) / 64, 256, 0, stream>>>(x, weight, attn,
                                                  Wh16, s_src, s_dst);
    k_prep<<<(N_EDGES + 255) / 256, 256, 0, stream>>>(eidx, flag, s32, d32,
                                                      rank, cnt);
    k_scan1<<<NB_SCAN, 256, 0, stream>>>(cnt, pre, bsum);
    k_scan2<<<1, 256, 0, stream>>>(bsum, bbase, off + N_NODES);
    k_scan3<<<NB_SCAN, 256, 0, stream>>>(pre, bbase, off);
    dim3 sg((N_EDGES + 255) / 256, NPASS);
    k_scatter<<<sg, 256, 0, stream>>>(s32, d32, rank, off, csr);
    k_node<<<N_NODES / 4, 256, 0, stream>>>(off, csr, s_src, s_dst,
                                            Wh16, mxb, invb, out_h);
    k_alpha<<<(N_EDGES + 255) / 256, 256, 0, stream>>>(s32, d32, s_src, s_dst,
                                                       mxb, invb, ebuf);
}

// Round 5
// 331.071 us; speedup vs baseline: 4.7277x; 1.1492x over previous
//
#include <hip/hip_runtime.h>
#include <hip/hip_bf16.h>
#include <math.h>

#define N_NODES 50000
#define N_EDGES 1600000
#define IN_DIM  128
#define OUT_DIM 32
#define N_HEADS 4
#define WH_DIM  (N_HEADS * OUT_DIM)   // 128
#define CAP     128                   // per-node LDS edge cache (max deg ~58)
#define NB_SCAN 196                   // ceil(50000/256)
#define NPASS   4                     // scatter dst-windows
#define WIN     ((N_NODES + NPASS - 1) / NPASS)   // 12500

typedef __attribute__((ext_vector_type(8))) short short8;     // 8 bf16
typedef __attribute__((ext_vector_type(4))) float floatx4;    // MFMA acc

__device__ __forceinline__ short f2bf(float v) {
    __hip_bfloat16 b = __float2bfloat16(v);
    return *reinterpret_cast<short*>(&b);
}
__device__ __forceinline__ float lrelu(float v) {
    return v > 0.0f ? v : 0.2f * v;
}

// ---------------------------------------------------------------------------
// edge_index may arrive as int32 or int64 (reference dtype). For int64, odd
// 32-bit words are zero hi-words; sample 256 of them.
// ---------------------------------------------------------------------------
__device__ __forceinline__ void load_edge(const void* eidx, int is32, int e,
                                          int& s, int& d) {
    if (is32) {
        const int2 v = ((const int2*)eidx)[e];
        s = v.x; d = v.y;
    } else {
        const longlong2 v = ((const longlong2*)eidx)[e];
        s = (int)v.x; d = (int)v.y;
    }
}

__global__ void k_detect(const int* __restrict__ eidx, int* __restrict__ flag) {
    int i = threadIdx.x;
    int r = eidx[2 * (i * (N_EDGES / 256)) + 1];
    if (r != 0) atomicOr(flag, 1);             // nonzero hi-word => int32
}

// ---------------------------------------------------------------------------
// MFMA GEMM: [64 nodes] x [144 cols] per block, K=128, bf16 inputs.
//   cols   0..127 : Wh  (bf16 out)
//   cols 128..135 : s = x . U where U[k][c] = sum_o W[h][k][o]*a[h][o]
//                   (c<4: a_src head c ; c>=4: a_dst head c-4)  -> f32 out
// A/B frags pre-swizzled in LDS so each fragment is one ds_read_b128.
// mfma_f32_16x16x32_bf16: A[m=lane&15][k=quad*8+j], B[k=quad*8+j][n=lane&15],
// C[row=quad*4+reg][col=lane&15]  (learn_hip verified layouts).
// ---------------------------------------------------------------------------
__global__ __launch_bounds__(256) void k_wh(
        const float* __restrict__ x, const float* __restrict__ weight,
        const float* __restrict__ attn,
        __hip_bfloat16* __restrict__ Wh16, float* __restrict__ sb8) {
    __shared__ float ubuf[128 * 8];            // 4 KB
    __shared__ short xsw[4 * 4 * 64 * 8];      // 16 KB  [wg][kc][lane][j]
    __shared__ short bsw[4 * 9 * 64 * 8];      // 36 KB  [kc][cg][lane][j]
    const int t  = threadIdx.x;
    const int nb = blockIdx.x * 64;

    // ---- U[k][c], c in [0,8)
    {
        int c = t & 7, k0 = t >> 3;            // k0 in [0,32)
        int h = c & 3;
        const float* ap = attn + h * 64 + (c >> 2) * 32;
        for (int k = k0; k < 128; k += 32) {
            const float* wp = weight + h * (IN_DIM * OUT_DIM) + k * OUT_DIM;
            float u = 0.f;
#pragma unroll
            for (int o = 0; o < 32; o += 4) {
                float4 wv = *(const float4*)(wp + o);
                float4 av = *(const float4*)(ap + o);
                u += wv.x * av.x + wv.y * av.y + wv.z * av.z + wv.w * av.w;
            }
            ubuf[k * 8 + c] = u;
        }
    }
    __syncthreads();

    // ---- stage B: weight cols 0..127
    for (int f = t; f < 128 * 128; f += 256) {
        int k = f >> 7, c = f & 127;
        float w = weight[(c >> 5) * (IN_DIM * OUT_DIM) + k * OUT_DIM + (c & 31)];
        int kc = k >> 5, quad = (k >> 3) & 3, j = k & 7;
        bsw[((kc * 9 + (c >> 4)) * 64 + quad * 16 + (c & 15)) * 8 + j] = f2bf(w);
    }
    // ---- stage B: extension cols 128..143 (U, zero-padded)
    for (int f = t; f < 128 * 16; f += 256) {
        int k = f >> 4, c = f & 15;
        float w = (c < 8) ? ubuf[k * 8 + c] : 0.f;
        int kc = k >> 5, quad = (k >> 3) & 3, j = k & 7;
        bsw[((kc * 9 + 8) * 64 + quad * 16 + c) * 8 + j] = f2bf(w);
    }
    // ---- stage A: 64 node rows of x, f32 -> bf16, swizzled
    for (int f = t; f < 64 * 32; f += 256) {
        int n = f >> 5, k = (f & 31) * 4;
        int ng = nb + n; if (ng > N_NODES - 1) ng = N_NODES - 1;
        float4 v = *(const float4*)(x + (size_t)ng * IN_DIM + k);
        int wg = n >> 4, m = n & 15, kc = k >> 5, quad = (k >> 3) & 3, j = k & 7;
        short4 sv = make_short4(f2bf(v.x), f2bf(v.y), f2bf(v.z), f2bf(v.w));
        *(short4*)&xsw[(((wg * 4 + kc) * 64) + quad * 16 + m) * 8 + j] = sv;
    }
    __syncthreads();

    // ---- compute: per wave, 16 nodes x 144 cols, 36 MFMAs
    const int wg = t >> 6, lane = t & 63;
    floatx4 acc[9];
#pragma unroll
    for (int i = 0; i < 9; ++i) acc[i] = (floatx4){0.f, 0.f, 0.f, 0.f};
#pragma unroll
    for (int kc = 0; kc < 4; ++kc) {
        short8 a = *(short8*)&xsw[((wg * 4 + kc) * 64 + lane) * 8];
#pragma unroll
        for (int cg = 0; cg < 9; ++cg) {
            short8 b = *(short8*)&bsw[((kc * 9 + cg) * 64 + lane) * 8];
            acc[cg] = __builtin_amdgcn_mfma_f32_16x16x32_bf16(a, b, acc[cg],
                                                              0, 0, 0);
        }
    }

    // ---- epilogue
    const int col = lane & 15, quad = lane >> 4;
#pragma unroll
    for (int r = 0; r < 4; ++r) {
        int n = nb + wg * 16 + quad * 4 + r;
        if (n >= N_NODES) continue;
#pragma unroll
        for (int cg = 0; cg < 8; ++cg)
            Wh16[(size_t)n * WH_DIM + cg * 16 + col] =
                __float2bfloat16(acc[cg][r]);
        if (col < 8) sb8[(size_t)n * 8 + col] = acc[8][r];
    }
}

// ---------------------------------------------------------------------------
// k_prep: canonicalize edges to int32 SoA + per-edge rank within dst segment
// ---------------------------------------------------------------------------
__global__ __launch_bounds__(256) void k_prep(
        const void* __restrict__ eidx, const int* __restrict__ flag,
        int* __restrict__ s32, int* __restrict__ d32,
        int* __restrict__ rank, int* __restrict__ cnt) {
    int e = blockIdx.x * 256 + threadIdx.x;
    if (e >= N_EDGES) return;
    int s, d;
    load_edge(eidx, *flag, e, s, d);
    s32[e] = s;
    d32[e] = d;
    rank[e] = atomicAdd(cnt + d, 1);
}

// ---------------------------------------------------------------------------
// 2-phase scan; consumers compute off[n] = pre[n] + bbase[n>>8] inline.
// ---------------------------------------------------------------------------
__global__ __launch_bounds__(256) void k_scan1(
        const int* __restrict__ cnt, int* __restrict__ pre,
        int* __restrict__ bsum) {
    __shared__ int sh[256];
    const int t = threadIdx.x;
    const int i = blockIdx.x * 256 + t;
    int v = (i < N_NODES) ? cnt[i] : 0;
    sh[t] = v;
    __syncthreads();
    for (int d = 1; d < 256; d <<= 1) {
        int u = (t >= d) ? sh[t - d] : 0;
        __syncthreads();
        sh[t] += u;
        __syncthreads();
    }
    if (i < N_NODES) pre[i] = sh[t] - v;
    if (t == 255) bsum[blockIdx.x] = sh[255];
}

__global__ __launch_bounds__(256) void k_scan2(
        const int* __restrict__ bsum, int* __restrict__ bbase) {
    __shared__ int sh[256];
    const int t = threadIdx.x;
    int v = (t < NB_SCAN) ? bsum[t] : 0;
    sh[t] = v;
    __syncthreads();
    for (int d = 1; d < 256; d <<= 1) {
        int u = (t >= d) ? sh[t - d] : 0;
        __syncthreads();
        sh[t] += u;
        __syncthreads();
    }
    if (t < NB_SCAN) bbase[t] = sh[t] - v;
}

// ---------------------------------------------------------------------------
// Windowed atomic-free scatter: pass y handles dst in [y*WIN, (y+1)*WIN).
// ---------------------------------------------------------------------------
__global__ __launch_bounds__(256) void k_scatter(
        const int* __restrict__ s32, const int* __restrict__ d32,
        const int* __restrict__ rank, const int* __restrict__ pre,
        const int* __restrict__ bbase, int* __restrict__ csr) {
    int e = blockIdx.x * 256 + threadIdx.x;
    if (e >= N_EDGES) return;
    int d = d32[e];
    if ((unsigned)(d - blockIdx.y * WIN) >= WIN) return;
    csr[pre[d] + bbase[d >> 8] + rank[e]] = s32[e];
}

// ---------------------------------------------------------------------------
// One wave per dst node. No max pass (softmax is shift-invariant; |e|<~9 so
// exp is safe in f32). Writes inv only; k_alpha recomputes alpha coalesced.
// ---------------------------------------------------------------------------
__global__ __launch_bounds__(256) void k_node(
        const int* __restrict__ pre, const int* __restrict__ bbase,
        const int* __restrict__ csr, const float* __restrict__ sb8,
        const __hip_bfloat16* __restrict__ Wh16,
        float* __restrict__ invb, float* __restrict__ out_h) {
    __shared__ int    sbuf[4][CAP];
    __shared__ float4 e4b[4][CAP];                      // exp(e) values
    const int wv = threadIdx.x >> 6;
    const int t  = threadIdx.x & 63;
    const int n  = blockIdx.x * 4 + wv;
    const int beg = pre[n] + bbase[n >> 8];
    const int end = (n + 1 < N_NODES) ? pre[n + 1] + bbase[(n + 1) >> 8]
                                      : N_EDGES;
    const int deg = end - beg;

    const float4 sd = *(const float4*)(sb8 + (size_t)n * 8 + 4);

    // Phase A: ex = exp(lrelu(s_src[src] + s_dst[n])); cache; running sum
    float4 sum = {0.f, 0.f, 0.f, 0.f};
    for (int l = t; l < deg; l += 64) {
        int s = csr[beg + l];
        float4 ss = *(const float4*)(sb8 + (size_t)s * 8);
        float4 ex;
        ex.x = __expf(lrelu(ss.x + sd.x));
        ex.y = __expf(lrelu(ss.y + sd.y));
        ex.z = __expf(lrelu(ss.z + sd.z));
        ex.w = __expf(lrelu(ss.w + sd.w));
        if (l < CAP) { sbuf[wv][l] = s; e4b[wv][l] = ex; }
        sum.x += ex.x; sum.y += ex.y; sum.z += ex.z; sum.w += ex.w;
    }
#pragma unroll
    for (int o = 32; o; o >>= 1) {
        sum.x += __shfl_xor(sum.x, o);
        sum.y += __shfl_xor(sum.y, o);
        sum.z += __shfl_xor(sum.z, o);
        sum.w += __shfl_xor(sum.w, o);
    }
    float4 inv;
    inv.x = 1.0f / (sum.x + 1e-9f); inv.y = 1.0f / (sum.y + 1e-9f);
    inv.z = 1.0f / (sum.z + 1e-9f); inv.w = 1.0f / (sum.w + 1e-9f);
    if (t == 0) *(float4*)(invb + (size_t)n * 4) = inv;

    // Phase D: out[n, :] = sum_j (ex_j[h]*inv[h]) * Wh16[src_j, :]
    const int h = t >> 4;
    const float invh = (h == 0) ? inv.x : (h == 1) ? inv.y
                     : (h == 2) ? inv.z : inv.w;
    float2 acc = {0.0f, 0.0f};
    if (deg <= CAP) {
        int j = 0;
        for (; j + 3 < deg; j += 4) {
            int s0 = sbuf[wv][j],     s1 = sbuf[wv][j + 1];
            int s2 = sbuf[wv][j + 2], s3 = sbuf[wv][j + 3];
            float a0 = ((const float*)&e4b[wv][j])[h]     * invh;
            float a1 = ((const float*)&e4b[wv][j + 1])[h] * invh;
            float a2 = ((const float*)&e4b[wv][j + 2])[h] * invh;
            float a3 = ((const float*)&e4b[wv][j + 3])[h] * invh;
            __hip_bfloat162 w0 = ((const __hip_bfloat162*)(Wh16 + (size_t)s0 * WH_DIM))[t];
            __hip_bfloat162 w1 = ((const __hip_bfloat162*)(Wh16 + (size_t)s1 * WH_DIM))[t];
            __hip_bfloat162 w2 = ((const __hip_bfloat162*)(Wh16 + (size_t)s2 * WH_DIM))[t];
            __hip_bfloat162 w3 = ((const __hip_bfloat162*)(Wh16 + (size_t)s3 * WH_DIM))[t];
            float2 f0 = __bfloat1622float2(w0);
            float2 f1 = __bfloat1622float2(w1);
            float2 f2 = __bfloat1622float2(w2);
            float2 f3 = __bfloat1622float2(w3);
            acc.x += a0 * f0.x + a1 * f1.x + a2 * f2.x + a3 * f3.x;
            acc.y += a0 * f0.y + a1 * f1.y + a2 * f2.y + a3 * f3.y;
        }
        for (; j < deg; ++j) {
            int s0 = sbuf[wv][j];
            float a0 = ((const float*)&e4b[wv][j])[h] * invh;
            __hip_bfloat162 w0 = ((const __hip_bfloat162*)(Wh16 + (size_t)s0 * WH_DIM))[t];
            float2 f0 = __bfloat1622float2(w0);
            acc.x += a0 * f0.x;
            acc.y += a0 * f0.y;
        }
    } else {
        float dh = (h == 0) ? sd.x : (h == 1) ? sd.y : (h == 2) ? sd.z : sd.w;
        for (int j = 0; j < deg; ++j) {
            int s0; float a0;
            if (j < CAP) {
                s0 = sbuf[wv][j];
                a0 = ((const float*)&e4b[wv][j])[h] * invh;
            } else {
                s0 = csr[beg + j];
                float sh = sb8[(size_t)s0 * 8 + h];
                a0 = __expf(lrelu(sh + dh)) * invh;
            }
            __hip_bfloat162 w0 = ((const __hip_bfloat162*)(Wh16 + (size_t)s0 * WH_DIM))[t];
            float2 f0 = __bfloat1622float2(w0);
            acc.x += a0 * f0.x;
            acc.y += a0 * f0.y;
        }
    }
    *(float2*)(out_h + (size_t)n * WH_DIM + 2 * t) = acc;
}

// ---------------------------------------------------------------------------
// Edge-parallel alpha: coalesced read of edges, coalesced float4 write.
// ---------------------------------------------------------------------------
__global__ __launch_bounds__(256) void k_alpha(
        const int* __restrict__ s32, const int* __restrict__ d32,
        const float* __restrict__ sb8, const float* __restrict__ invb,
        float* __restrict__ ebuf) {
    int e = blockIdx.x * 256 + threadIdx.x;
    if (e >= N_EDGES) return;
    int s = s32[e], d = d32[e];
    float4 ss = *(const float4*)(sb8 + (size_t)s * 8);
    float4 sd = *(const float4*)(sb8 + (size_t)d * 8 + 4);
    float4 iv = *(const float4*)(invb + (size_t)d * 4);
    float4 a;
    a.x = __expf(lrelu(ss.x + sd.x)) * iv.x;
    a.y = __expf(lrelu(ss.y + sd.y)) * iv.y;
    a.z = __expf(lrelu(ss.z + sd.z)) * iv.z;
    a.w = __expf(lrelu(ss.w + sd.w)) * iv.w;
    *(float4*)(ebuf + (size_t)e * 4) = a;
}

// ---------------------------------------------------------------------------
extern "C" void kernel_launch(void* const* d_in, const int* in_sizes, int n_in,
                              void* d_out, int out_size, void* d_ws, size_t ws_size,
                              hipStream_t stream) {
    const float* x      = (const float*)d_in[0];
    const void*  eidx   = d_in[1];
    const float* weight = (const float*)d_in[2];
    const float* attn   = (const float*)d_in[3];

    float* out   = (float*)d_out;
    float* out_h = out;                                   // [N_NODES, 128]
    float* ebuf  = out + (size_t)N_NODES * WH_DIM;        // [N_EDGES, 4] alpha

    // workspace layout (64-B aligned); total 40.4 MB
    char* ws = (char*)d_ws;
    int*   cnt   = (int*)ws;                              // 200000 B
    int*   flag  = (int*)(ws + 200064);
    int*   pre   = (int*)(ws + 200128);                   // 200000 B
    int*   bsum  = (int*)(ws + 400192);                   // 784 B
    int*   bbase = (int*)(ws + 401024);                   // 784 B
    int*   s32   = (int*)(ws + 401856);                   // 6.4 MB
    int*   d32   = (int*)(ws + 6801856);                  // 6.4 MB
    int*   rank  = (int*)(ws + 13201856);                 // 6.4 MB
    int*   csr   = (int*)(ws + 19601856);                 // 6.4 MB
    __hip_bfloat16* Wh16 = (__hip_bfloat16*)(ws + 26001856);  // 12.8 MB
    float* sb8   = (float*)(ws + 38801856);               // 1.6 MB  [n][8]
    float* invb  = (float*)(ws + 13201856);               // aliases rank (dead after scatter)

    hipMemsetAsync(ws, 0, 200068, stream);                // cnt + flag

    k_detect<<<1, 256, 0, stream>>>((const int*)eidx, flag);
    k_wh<<<(N_NODES + 63) / 64, 256, 0, stream>>>(x, weight, attn, Wh16, sb8);
    k_prep<<<(N_EDGES + 255) / 256, 256, 0, stream>>>(eidx, flag, s32, d32,
                                                      rank, cnt);
    k_scan1<<<NB_SCAN, 256, 0, stream>>>(cnt, pre, bsum);
    k_scan2<<<1, 256, 0, stream>>>(bsum, bbase);
    dim3 sg((N_EDGES + 255) / 256, NPASS);
    k_scatter<<<sg, 256, 0, stream>>>(s32, d32, rank, pre, bbase, csr);
    k_node<<<N_NODES / 4, 256, 0, stream>>>(pre, bbase, csr, sb8,
                                            Wh16, invb, out_h);
    k_alpha<<<(N_EDGES + 255) / 256, 256, 0, stream>>>(s32, d32, sb8,
                                                       invb, ebuf);
}

// Round 6
// 282.699 us; speedup vs baseline: 5.5366x; 1.1711x over previous
//
#include <hip/hip_runtime.h>
#include <hip/hip_bf16.h>
#include <math.h>

#define N_NODES 50000
#define N_EDGES 1600000
#define IN_DIM  128
#define OUT_DIM 32
#define N_HEADS 4
#define WH_DIM  (N_HEADS * OUT_DIM)   // 128
#define CAP     128                   // per-node LDS edge cache (max deg ~58)
#define NB_SCAN 196                   // ceil(50000/256)
#define NPASS   4                     // dst-windows
#define WIN     (N_NODES / NPASS)     // 12500
#define NCHUNK  32                    // edge chunks for counting sort
#define CE      (N_EDGES / NCHUNK)    // 50000 edges per chunk

typedef __attribute__((ext_vector_type(8))) short short8;     // 8 bf16
typedef __attribute__((ext_vector_type(4))) float floatx4;    // MFMA acc

__device__ __forceinline__ short f2bf(float v) {
    __hip_bfloat16 b = __float2bfloat16(v);
    return *reinterpret_cast<short*>(&b);
}
__device__ __forceinline__ float lrelu(float v) {
    return v > 0.0f ? v : 0.2f * v;
}

// ---------------------------------------------------------------------------
// edge_index may arrive as int32 or int64 (reference dtype). For int64, odd
// 32-bit words are zero hi-words; sample 256 of them.
// ---------------------------------------------------------------------------
__device__ __forceinline__ void load_edge(const void* eidx, int is32, int e,
                                          int& s, int& d) {
    if (is32) {
        const int2 v = ((const int2*)eidx)[e];
        s = v.x; d = v.y;
    } else {
        const longlong2 v = ((const longlong2*)eidx)[e];
        s = (int)v.x; d = (int)v.y;
    }
}

__global__ void k_detect(const int* __restrict__ eidx, int* __restrict__ flag) {
    int i = threadIdx.x;
    int r = eidx[2 * (i * (N_EDGES / 256)) + 1];
    if (r != 0) atomicOr(flag, 1);             // nonzero hi-word => int32
}

// ---------------------------------------------------------------------------
// k_cvt: canonicalize edges to int32 SoA (coalesced, no atomics)
// ---------------------------------------------------------------------------
__global__ __launch_bounds__(256) void k_cvt(
        const void* __restrict__ eidx, const int* __restrict__ flag,
        int* __restrict__ s32, int* __restrict__ d32) {
    int e = blockIdx.x * 256 + threadIdx.x;
    if (e >= N_EDGES) return;
    int s, d;
    load_edge(eidx, *flag, e, s, d);
    s32[e] = s;
    d32[e] = d;
}

// ---------------------------------------------------------------------------
// MFMA GEMM: [64 nodes] x [144 cols] per block, K=128, bf16 inputs.
//   cols   0..127 : Wh  (bf16 out)
//   cols 128..135 : s = x . U where U[k][c] = sum_o W[h][k][o]*a[h][o]
//                   (c<4: a_src head c ; c>=4: a_dst head c-4)  -> f32 out
// ---------------------------------------------------------------------------
__global__ __launch_bounds__(256) void k_wh(
        const float* __restrict__ x, const float* __restrict__ weight,
        const float* __restrict__ attn,
        __hip_bfloat16* __restrict__ Wh16, float* __restrict__ sb16) {
    __shared__ float ubuf[128 * 8];            // 4 KB
    __shared__ short xsw[4 * 4 * 64 * 8];      // 16 KB  [wg][kc][lane][j]
    __shared__ short bsw[4 * 9 * 64 * 8];      // 36 KB  [kc][cg][lane][j]
    const int t  = threadIdx.x;
    const int nb = blockIdx.x * 64;

    // ---- U[k][c], c in [0,8)
    {
        int c = t & 7, k0 = t >> 3;            // k0 in [0,32)
        int h = c & 3;
        const float* ap = attn + h * 64 + (c >> 2) * 32;
        for (int k = k0; k < 128; k += 32) {
            const float* wp = weight + h * (IN_DIM * OUT_DIM) + k * OUT_DIM;
            float u = 0.f;
#pragma unroll
            for (int o = 0; o < 32; o += 4) {
                float4 wv = *(const float4*)(wp + o);
                float4 av = *(const float4*)(ap + o);
                u += wv.x * av.x + wv.y * av.y + wv.z * av.z + wv.w * av.w;
            }
            ubuf[k * 8 + c] = u;
        }
    }
    __syncthreads();

    // ---- stage B: weight cols 0..127
    for (int f = t; f < 128 * 128; f += 256) {
        int k = f >> 7, c = f & 127;
        float w = weight[(c >> 5) * (IN_DIM * OUT_DIM) + k * OUT_DIM + (c & 31)];
        int kc = k >> 5, quad = (k >> 3) & 3, j = k & 7;
        bsw[((kc * 9 + (c >> 4)) * 64 + quad * 16 + (c & 15)) * 8 + j] = f2bf(w);
    }
    // ---- stage B: extension cols 128..143 (U, zero-padded)
    for (int f = t; f < 128 * 16; f += 256) {
        int k = f >> 4, c = f & 15;
        float w = (c < 8) ? ubuf[k * 8 + c] : 0.f;
        int kc = k >> 5, quad = (k >> 3) & 3, j = k & 7;
        bsw[((kc * 9 + 8) * 64 + quad * 16 + c) * 8 + j] = f2bf(w);
    }
    // ---- stage A: 64 node rows of x, f32 -> bf16, swizzled
    for (int f = t; f < 64 * 32; f += 256) {
        int n = f >> 5, k = (f & 31) * 4;
        int ng = nb + n; if (ng > N_NODES - 1) ng = N_NODES - 1;
        float4 v = *(const float4*)(x + (size_t)ng * IN_DIM + k);
        int wg = n >> 4, m = n & 15, kc = k >> 5, quad = (k >> 3) & 3, j = k & 7;
        short4 sv = make_short4(f2bf(v.x), f2bf(v.y), f2bf(v.z), f2bf(v.w));
        *(short4*)&xsw[(((wg * 4 + kc) * 64) + quad * 16 + m) * 8 + j] = sv;
    }
    __syncthreads();

    // ---- compute: per wave, 16 nodes x 144 cols, 36 MFMAs
    const int wg = t >> 6, lane = t & 63;
    floatx4 acc[9];
#pragma unroll
    for (int i = 0; i < 9; ++i) acc[i] = (floatx4){0.f, 0.f, 0.f, 0.f};
#pragma unroll
    for (int kc = 0; kc < 4; ++kc) {
        short8 a = *(short8*)&xsw[((wg * 4 + kc) * 64 + lane) * 8];
#pragma unroll
        for (int cg = 0; cg < 9; ++cg) {
            short8 b = *(short8*)&bsw[((kc * 9 + cg) * 64 + lane) * 8];
            acc[cg] = __builtin_amdgcn_mfma_f32_16x16x32_bf16(a, b, acc[cg],
                                                              0, 0, 0);
        }
    }

    // ---- epilogue
    const int col = lane & 15, quad = lane >> 4;
#pragma unroll
    for (int r = 0; r < 4; ++r) {
        int n = nb + wg * 16 + quad * 4 + r;
        if (n >= N_NODES) continue;
#pragma unroll
        for (int cg = 0; cg < 8; ++cg)
            Wh16[(size_t)n * WH_DIM + cg * 16 + col] =
                __float2bfloat16(acc[cg][r]);
        if (col < 8) sb16[(size_t)n * 16 + col] = acc[8][r];
    }
}

// ---------------------------------------------------------------------------
// k_hist: (chunk, window) blocks; LDS histogram, coalesced flush, no atomics.
// ---------------------------------------------------------------------------
__global__ __launch_bounds__(1024) void k_hist(
        const int* __restrict__ d32, int* __restrict__ hist) {
    __shared__ int hbin[WIN];                  // 50 KB
    const int c = blockIdx.x, w = blockIdx.y;
    for (int i = threadIdx.x; i < WIN; i += 1024) hbin[i] = 0;
    __syncthreads();
    const int w0 = w * WIN;
    for (int e = c * CE + threadIdx.x; e < (c + 1) * CE; e += 1024) {
        unsigned u = (unsigned)(d32[e] - w0);
        if (u < WIN) atomicAdd(&hbin[u], 1);
    }
    __syncthreads();
    for (int i = threadIdx.x; i < WIN; i += 1024)
        hist[c * N_NODES + w0 + i] = hbin[i];
}

// ---------------------------------------------------------------------------
// scan: per-dst total over chunks + hierarchical exclusive scan
// off[n] = pre[n] + bbase[n>>8]
// ---------------------------------------------------------------------------
__global__ __launch_bounds__(256) void k_scan1(
        const int* __restrict__ hist, int* __restrict__ pre,
        int* __restrict__ bsum) {
    __shared__ int sh[256];
    const int t = threadIdx.x;
    const int i = blockIdx.x * 256 + t;
    int v = 0;
    if (i < N_NODES)
        for (int c = 0; c < NCHUNK; ++c) v += hist[c * N_NODES + i];
    sh[t] = v;
    __syncthreads();
    for (int d = 1; d < 256; d <<= 1) {
        int u = (t >= d) ? sh[t - d] : 0;
        __syncthreads();
        sh[t] += u;
        __syncthreads();
    }
    if (i < N_NODES) pre[i] = sh[t] - v;
    if (t == 255) bsum[blockIdx.x] = sh[255];
}

__global__ __launch_bounds__(256) void k_scan2(
        const int* __restrict__ bsum, int* __restrict__ bbase) {
    __shared__ int sh[256];
    const int t = threadIdx.x;
    int v = (t < NB_SCAN) ? bsum[t] : 0;
    sh[t] = v;
    __syncthreads();
    for (int d = 1; d < 256; d <<= 1) {
        int u = (t >= d) ? sh[t - d] : 0;
        __syncthreads();
        sh[t] += u;
        __syncthreads();
    }
    if (t < NB_SCAN) bbase[t] = sh[t] - v;
}

// ---------------------------------------------------------------------------
// k_base: in place, hist[c][d] := off[d] + sum_{c'<c} hist[c'][d]
// ---------------------------------------------------------------------------
__global__ __launch_bounds__(256) void k_base(
        const int* __restrict__ pre, const int* __restrict__ bbase,
        int* __restrict__ hist) {
    int d = blockIdx.x * 256 + threadIdx.x;
    if (d >= N_NODES) return;
    int run = pre[d] + bbase[d >> 8];
    for (int c = 0; c < NCHUNK; ++c) {
        int t0 = hist[c * N_NODES + d];
        hist[c * N_NODES + d] = run;
        run += t0;
    }
}

// ---------------------------------------------------------------------------
// k_scatter: (chunk, window) blocks; positions via LDS atomics on bases.
// Window csr region ~1.6 MB stays L2-resident (R4-proven pattern).
// ---------------------------------------------------------------------------
__global__ __launch_bounds__(1024) void k_scatter(
        const int* __restrict__ s32, const int* __restrict__ d32,
        const int* __restrict__ hist, int* __restrict__ csr) {
    __shared__ int pos[WIN];                   // 50 KB
    const int c = blockIdx.x, w = blockIdx.y;
    const int w0 = w * WIN;
    for (int i = threadIdx.x; i < WIN; i += 1024)
        pos[i] = hist[c * N_NODES + w0 + i];
    __syncthreads();
    for (int e = c * CE + threadIdx.x; e < (c + 1) * CE; e += 1024) {
        unsigned u = (unsigned)(d32[e] - w0);
        if (u < WIN) {
            int p = atomicAdd(&pos[u], 1);
            csr[p] = s32[e];
        }
    }
}

// ---------------------------------------------------------------------------
// One wave per dst node. No max pass (softmax shift-invariant; |e| small).
// sb16 row: [0..3]=s_src, [4..7]=s_dst, [8..11]=inv (written here), 64 B.
// ---------------------------------------------------------------------------
__global__ __launch_bounds__(256) void k_node(
        const int* __restrict__ pre, const int* __restrict__ bbase,
        const int* __restrict__ csr, float* __restrict__ sb16,
        const __hip_bfloat16* __restrict__ Wh16,
        float* __restrict__ out_h) {
    __shared__ int    sbuf[4][CAP];
    __shared__ float4 e4b[4][CAP];                      // exp(e) values
    const int wv = threadIdx.x >> 6;
    const int t  = threadIdx.x & 63;
    const int n  = blockIdx.x * 4 + wv;
    const int beg = pre[n] + bbase[n >> 8];
    const int end = (n + 1 < N_NODES) ? pre[n + 1] + bbase[(n + 1) >> 8]
                                      : N_EDGES;
    const int deg = end - beg;

    const float4 sd = *(const float4*)(sb16 + (size_t)n * 16 + 4);

    // Phase A: ex = exp(lrelu(s_src[src] + s_dst[n])); cache; running sum
    float4 sum = {0.f, 0.f, 0.f, 0.f};
    for (int l = t; l < deg; l += 64) {
        int s = csr[beg + l];
        float4 ss = *(const float4*)(sb16 + (size_t)s * 16);
        float4 ex;
        ex.x = __expf(lrelu(ss.x + sd.x));
        ex.y = __expf(lrelu(ss.y + sd.y));
        ex.z = __expf(lrelu(ss.z + sd.z));
        ex.w = __expf(lrelu(ss.w + sd.w));
        if (l < CAP) { sbuf[wv][l] = s; e4b[wv][l] = ex; }
        sum.x += ex.x; sum.y += ex.y; sum.z += ex.z; sum.w += ex.w;
    }
#pragma unroll
    for (int o = 32; o; o >>= 1) {
        sum.x += __shfl_xor(sum.x, o);
        sum.y += __shfl_xor(sum.y, o);
        sum.z += __shfl_xor(sum.z, o);
        sum.w += __shfl_xor(sum.w, o);
    }
    float4 inv;
    inv.x = 1.0f / (sum.x + 1e-9f); inv.y = 1.0f / (sum.y + 1e-9f);
    inv.z = 1.0f / (sum.z + 1e-9f); inv.w = 1.0f / (sum.w + 1e-9f);
    if (t == 0) *(float4*)(sb16 + (size_t)n * 16 + 8) = inv;

    // Phase D: out[n, :] = sum_j (ex_j[h]*inv[h]) * Wh16[src_j, :]
    const int h = t >> 4;
    const float invh = (h == 0) ? inv.x : (h == 1) ? inv.y
                     : (h == 2) ? inv.z : inv.w;
    float2 acc = {0.0f, 0.0f};
    if (deg <= CAP) {
        int j = 0;
        for (; j + 3 < deg; j += 4) {
            int s0 = sbuf[wv][j],     s1 = sbuf[wv][j + 1];
            int s2 = sbuf[wv][j + 2], s3 = sbuf[wv][j + 3];
            float a0 = ((const float*)&e4b[wv][j])[h]     * invh;
            float a1 = ((const float*)&e4b[wv][j + 1])[h] * invh;
            float a2 = ((const float*)&e4b[wv][j + 2])[h] * invh;
            float a3 = ((const float*)&e4b[wv][j + 3])[h] * invh;
            __hip_bfloat162 w0 = ((const __hip_bfloat162*)(Wh16 + (size_t)s0 * WH_DIM))[t];
            __hip_bfloat162 w1 = ((const __hip_bfloat162*)(Wh16 + (size_t)s1 * WH_DIM))[t];
            __hip_bfloat162 w2 = ((const __hip_bfloat162*)(Wh16 + (size_t)s2 * WH_DIM))[t];
            __hip_bfloat162 w3 = ((const __hip_bfloat162*)(Wh16 + (size_t)s3 * WH_DIM))[t];
            float2 f0 = __bfloat1622float2(w0);
            float2 f1 = __bfloat1622float2(w1);
            float2 f2 = __bfloat1622float2(w2);
            float2 f3 = __bfloat1622float2(w3);
            acc.x += a0 * f0.x + a1 * f1.x + a2 * f2.x + a3 * f3.x;
            acc.y += a0 * f0.y + a1 * f1.y + a2 * f2.y + a3 * f3.y;
        }
        for (; j < deg; ++j) {
            int s0 = sbuf[wv][j];
            float a0 = ((const float*)&e4b[wv][j])[h] * invh;
            __hip_bfloat162 w0 = ((const __hip_bfloat162*)(Wh16 + (size_t)s0 * WH_DIM))[t];
            float2 f0 = __bfloat1622float2(w0);
            acc.x += a0 * f0.x;
            acc.y += a0 * f0.y;
        }
    } else {
        float dh = (h == 0) ? sd.x : (h == 1) ? sd.y : (h == 2) ? sd.z : sd.w;
        for (int j = 0; j < deg; ++j) {
            int s0; float a0;
            if (j < CAP) {
                s0 = sbuf[wv][j];
                a0 = ((const float*)&e4b[wv][j])[h] * invh;
            } else {
                s0 = csr[beg + j];
                float sh = sb16[(size_t)s0 * 16 + h];
                a0 = __expf(lrelu(sh + dh)) * invh;
            }
            __hip_bfloat162 w0 = ((const __hip_bfloat162*)(Wh16 + (size_t)s0 * WH_DIM))[t];
            float2 f0 = __bfloat1622float2(w0);
            acc.x += a0 * f0.x;
            acc.y += a0 * f0.y;
        }
    }
    *(float2*)(out_h + (size_t)n * WH_DIM + 2 * t) = acc;
}

// ---------------------------------------------------------------------------
// Edge-parallel alpha: coalesced edge reads; dst-side gather (sd+inv) hits
// one 64 B line per edge; coalesced float4 write.
// ---------------------------------------------------------------------------
__global__ __launch_bounds__(256) void k_alpha(
        const int* __restrict__ s32, const int* __restrict__ d32,
        const float* __restrict__ sb16, float* __restrict__ ebuf) {
    int e = blockIdx.x * 256 + threadIdx.x;
    if (e >= N_EDGES) return;
    int s = s32[e], d = d32[e];
    float4 ss = *(const float4*)(sb16 + (size_t)s * 16);
    float4 sd = *(const float4*)(sb16 + (size_t)d * 16 + 4);
    float4 iv = *(const float4*)(sb16 + (size_t)d * 16 + 8);
    float4 a;
    a.x = __expf(lrelu(ss.x + sd.x)) * iv.x;
    a.y = __expf(lrelu(ss.y + sd.y)) * iv.y;
    a.z = __expf(lrelu(ss.z + sd.z)) * iv.z;
    a.w = __expf(lrelu(ss.w + sd.w)) * iv.w;
    *(float4*)(ebuf + (size_t)e * 4) = a;
}

// ---------------------------------------------------------------------------
extern "C" void kernel_launch(void* const* d_in, const int* in_sizes, int n_in,
                              void* d_out, int out_size, void* d_ws, size_t ws_size,
                              hipStream_t stream) {
    const float* x      = (const float*)d_in[0];
    const void*  eidx   = d_in[1];
    const float* weight = (const float*)d_in[2];
    const float* attn   = (const float*)d_in[3];

    float* out   = (float*)d_out;
    float* out_h = out;                                   // [N_NODES, 128]
    float* ebuf  = out + (size_t)N_NODES * WH_DIM;        // [N_EDGES, 4] alpha

    // workspace layout (64-B aligned); total ~41.8 MB
    char* ws = (char*)d_ws;
    int*   flag  = (int*)ws;                              // 4 B
    int*   bsum  = (int*)(ws + 64);                       // 784 B
    int*   bbase = (int*)(ws + 896);                      // 784 B
    int*   pre   = (int*)(ws + 2048);                     // 200000 B
    int*   s32   = (int*)(ws + 202112);                   // 6.4 MB
    int*   d32   = (int*)(ws + 6602112);                  // 6.4 MB
    int*   hist  = (int*)(ws + 13002112);                 // 6.4 MB [c][d]
    int*   csr   = (int*)(ws + 19402112);                 // 6.4 MB
    __hip_bfloat16* Wh16 = (__hip_bfloat16*)(ws + 25802112);  // 12.8 MB
    float* sb16  = (float*)(ws + 38602112);               // 3.2 MB [n][16]

    hipMemsetAsync(flag, 0, 4, stream);

    k_detect<<<1, 256, 0, stream>>>((const int*)eidx, flag);
    k_cvt<<<(N_EDGES + 255) / 256, 256, 0, stream>>>(eidx, flag, s32, d32);
    k_wh<<<(N_NODES + 63) / 64, 256, 0, stream>>>(x, weight, attn, Wh16, sb16);
    dim3 hg(NCHUNK, NPASS);
    k_hist<<<hg, 1024, 0, stream>>>(d32, hist);
    k_scan1<<<NB_SCAN, 256, 0, stream>>>(hist, pre, bsum);
    k_scan2<<<1, 256, 0, stream>>>(bsum, bbase);
    k_base<<<NB_SCAN, 256, 0, stream>>>(pre, bbase, hist);
    k_scatter<<<hg, 1024, 0, stream>>>(s32, d32, hist, csr);
    k_node<<<N_NODES / 4, 256, 0, stream>>>(pre, bbase, csr, sb16,
                                            Wh16, out_h);
    k_alpha<<<(N_EDGES + 255) / 256, 256, 0, stream>>>(s32, d32, sb16, ebuf);
}